// Round 3
// baseline (421.970 us; speedup 1.0000x reference)
//
#include <hip/hip_runtime.h>
#include <math.h>

#define NB 4096

// ---- workspace layout (float offsets) ----
#define BARo  0               // 16 ints: grid barrier counters (zeroed by memset)
#define Ao    16              // B*4096
#define Do    (Ao+16384)
#define VGo   (Do+16384)      // B*4096*64
#define ASo   (VGo+1048576)   // sorted a
#define PERMo (ASo+16384)     // int
#define BSTo  (PERMo+16384)   // int, bucket starts
#define Po    (BSTo+16384)    // chunk partials [b][64][3][64]
#define PSEAo (Po+49152)      // chunk scalar partials sum(e^a) [b][64]
#define PSAo  (PSEAo+256)     // chunk scalar partials sum(a)   [b][64]
#define SA2o  (PSAo+256)      // [b][4097]
#define SB2o  (SA2o+16388)    // [b][4097]
#define To    (SB2o+16388)    // tables [b][4097][3][64]
// end = To + 3146496 = 4359448 floats (~17.4 MB)

__device__ __forceinline__ int bucket_of(float v) {
    int k = (int)((v + 16.0f) * 128.0f);
    k = k < 0 ? 0 : k;
    k = k > (NB - 1) ? (NB - 1) : k;
    return k;
}

__device__ __forceinline__ void gbar(int* bar, int n) {
    __syncthreads();
    __threadfence();                    // release: flush this block's writes (L2 wb)
    if (threadIdx.x == 0) {
        __hip_atomic_fetch_add(bar, 1, __ATOMIC_ACQ_REL, __HIP_MEMORY_SCOPE_AGENT);
        while (__hip_atomic_load(bar, __ATOMIC_ACQUIRE, __HIP_MEMORY_SCOPE_AGENT) < n)
            __builtin_amdgcn_s_sleep(2);
    }
    __syncthreads();
    __threadfence();                    // acquire: invalidate caches before reads
}

__global__ __launch_bounds__(256) void k_fused(
        const float* __restrict__ x,
        const float* __restrict__ Wq, const float* __restrict__ bq,
        const float* __restrict__ Wk, const float* __restrict__ bk,
        const float* __restrict__ wcq, const float* __restrict__ wck,
        const float* __restrict__ Wv, const float* __restrict__ bv,
        const float* __restrict__ Wg, const float* __restrict__ bg,
        float* __restrict__ ws, float* __restrict__ out) {
    __shared__ float smem[12800];       // 51.2 KB, overlaid per phase
    int tid = threadIdx.x;
    int bid = blockIdx.x;
    int b = bid >> 6, t6 = bid & 63;
    int* bar = (int*)ws + BARo;

    // ===== Phase A: weight prep (redundant per block) + projections =====
    {
        float* xt  = smem;              // [64][68]
        float* wt  = smem + 4352;       // [64][68]: wt[c][o] = Wvg[o][c]
        float* wqe = smem + 8704, *wke = smem + 8768, *bvg = smem + 8832, *misc = smem + 8896;
        if (tid < 64) {
            float s1 = 0.f, s2 = 0.f, s3 = 0.f;
            for (int o = 0; o < 16; o++) { s1 += wcq[o] * Wq[o * 64 + tid]; s2 += wck[o] * Wk[o * 64 + tid]; }
            for (int m = 0; m < 64; m++) s3 += Wg[tid * 64 + m] * bv[m];
            wqe[tid] = s1; wke[tid] = s2; bvg[tid] = s3;
        } else if (tid == 64) {
            float s = 0.f; for (int o = 0; o < 16; o++) s += wcq[o] * bq[o]; misc[0] = s;
        } else if (tid == 65) {
            float s = 0.f; for (int o = 0; o < 16; o++) s += wck[o] * bk[o]; misc[1] = s;
        }
        // Wvg = Wg @ Wv  (each thread: fixed o, 16 consecutive c)
        {
            int o = tid & 63, c0 = (tid >> 6) * 16;
            float acc[16];
#pragma unroll
            for (int k = 0; k < 16; k++) acc[k] = 0.f;
            for (int m = 0; m < 64; m++) {
                float wg = Wg[o * 64 + m];
                const float4* wv4 = (const float4*)(Wv + m * 64 + c0);
                float4 a0 = wv4[0], a1 = wv4[1], a2 = wv4[2], a3 = wv4[3];
                acc[0] += wg * a0.x; acc[1] += wg * a0.y; acc[2] += wg * a0.z; acc[3] += wg * a0.w;
                acc[4] += wg * a1.x; acc[5] += wg * a1.y; acc[6] += wg * a1.z; acc[7] += wg * a1.w;
                acc[8] += wg * a2.x; acc[9] += wg * a2.y; acc[10] += wg * a2.z; acc[11] += wg * a2.w;
                acc[12] += wg * a3.x; acc[13] += wg * a3.y; acc[14] += wg * a3.z; acc[15] += wg * a3.w;
            }
#pragma unroll
            for (int k = 0; k < 16; k++) wt[(c0 + k) * 68 + o] = acc[k];
        }
        const float* xb = x + (size_t)b * 64 * 4096;
        for (int idx = tid; idx < 4096; idx += 256) {
            int c = idx >> 6, nl = idx & 63;
            xt[c * 68 + nl] = xb[(size_t)c * 4096 + t6 * 64 + nl];
        }
        __syncthreads();
        if (tid < 64) {
            float s1 = misc[0], s2 = misc[1];
            for (int c = 0; c < 64; c++) {
                float xv = xt[c * 68 + tid];
                s1 += wqe[c] * xv; s2 += wke[c] * xv;
            }
            ws[Ao + b * 4096 + t6 * 64 + tid] = s1;
            ws[Do + b * 4096 + t6 * 64 + tid] = s2;
        }
        {
            int o = tid & 63, nl0 = (tid >> 6) * 16;
            float acc[16];
            float bo = bvg[o];
#pragma unroll
            for (int k = 0; k < 16; k++) acc[k] = bo;
            for (int c = 0; c < 64; c++) {
                float wv = wt[c * 68 + o];
                const float* xr = &xt[c * 68 + nl0];
#pragma unroll
                for (int k = 0; k < 16; k++) acc[k] += wv * xr[k];
            }
#pragma unroll
            for (int k = 0; k < 16; k++)
                ws[VGo + ((size_t)(b * 4096) + t6 * 64 + nl0 + k) * 64 + o] = acc[k];
        }
    }
    gbar(&bar[0], 256);

    // ===== Phase B: bucket quasi-sort of a (4 blocks, one per batch) =====
    if (bid < 4) {
        unsigned int* hist = (unsigned int*)smem;
        unsigned int* cnt  = hist + 4096;
        unsigned int* scanbuf = cnt + 4096;
        int bb = bid;
        const float* Ab = ws + Ao + bb * 4096;
        int* perm = (int*)ws + PERMo;
        int* bst  = (int*)ws + BSTo;
        for (int i = tid; i < NB; i += 256) { hist[i] = 0u; cnt[i] = 0u; }
        __syncthreads();
        for (int i = tid; i < 4096; i += 256) atomicAdd(&hist[bucket_of(Ab[i])], 1u);
        __syncthreads();
        unsigned int s = 0u; int base = tid * 16;
        for (int k = 0; k < 16; k++) s += hist[base + k];
        scanbuf[tid] = s;
        __syncthreads();
        for (int off = 1; off < 256; off <<= 1) {
            unsigned int v = scanbuf[tid];
            unsigned int u = (tid >= off) ? scanbuf[tid - off] : 0u;
            __syncthreads();
            scanbuf[tid] = v + u;
            __syncthreads();
        }
        unsigned int run = (tid > 0) ? scanbuf[tid - 1] : 0u;
        for (int k = 0; k < 16; k++) {
            unsigned int h = hist[base + k];
            hist[base + k] = run;
            bst[bb * NB + base + k] = (int)run;
            run += h;
        }
        __syncthreads();
        for (int i = tid; i < 4096; i += 256) {
            float av = Ab[i];
            int kb = bucket_of(av);
            unsigned int r = hist[kb] + atomicAdd(&cnt[kb], 1u);
            ws[ASo + bb * 4096 + r] = av;
            perm[bb * 4096 + r] = i;
        }
    }
    gbar(&bar[1], 256);

    // ===== Phase C: chunk partials; stash gathered values in registers =====
    int c = tid & 63, w = tid >> 6;
    int r0 = t6 * 64 + w * 16;
    float avs[16], eas[16], wvs[16];
    float s1 = 0.f, s2 = 0.f, s3 = 0.f, sea_w = 0.f, sa_w = 0.f;
    {
        const int* perm = (const int*)ws + PERMo;
#pragma unroll 4
        for (int k = 0; k < 16; k++) {
            int r = r0 + k;
            int p = perm[b * 4096 + r];
            float av = ws[ASo + b * 4096 + r];
            float ea = expf(av);
            float wv = ws[VGo + ((size_t)(b * 4096) + p) * 64 + c];
            avs[k] = av; eas[k] = ea; wvs[k] = wv;
            s1 += wv; s2 += wv * ea; s3 += wv * av;
            sea_w += ea; sa_w += av;
        }
        float* part = smem;
        part[(w * 3 + 0) * 64 + c] = s1;
        part[(w * 3 + 1) * 64 + c] = s2;
        part[(w * 3 + 2) * 64 + c] = s3;
        if (c == 0) { smem[768 + w] = sea_w; smem[772 + w] = sa_w; }
        __syncthreads();
        if (tid < 192) {
            int g = tid >> 6, cc = tid & 63;
            float s = part[(0 * 3 + g) * 64 + cc] + part[(1 * 3 + g) * 64 + cc]
                    + part[(2 * 3 + g) * 64 + cc] + part[(3 * 3 + g) * 64 + cc];
            ws[Po + ((b * 64 + t6) * 3 + g) * 64 + cc] = s;
        } else if (tid == 192) {
            ws[PSEAo + b * 64 + t6] = smem[768] + smem[769] + smem[770] + smem[771];
            ws[PSAo  + b * 64 + t6] = smem[772] + smem[773] + smem[774] + smem[775];
        }
    }
    gbar(&bar[2], 256);

    // ===== Phase D: scan chunk partials + chunk scalars (4 blocks) =====
    if (bid < 4) {
        int bb = bid;
        for (int i = tid; i < 12288; i += 256) smem[i] = ws[Po + bb * 12288 + i];
        if (tid < 64)       smem[12288 + tid] = ws[PSEAo + bb * 64 + tid];
        else if (tid < 128) smem[12288 + tid] = ws[PSAo + bb * 64 + tid - 64];
        __syncthreads();
        if (tid < 192) {
            float r = 0.f;
            for (int ch = 0; ch < 64; ch++) { float v = smem[ch * 192 + tid]; smem[ch * 192 + tid] = r; r += v; }
        } else if (tid == 192) {
            float r = 0.f;
            for (int ch = 0; ch < 64; ch++) { float v = smem[12288 + ch]; smem[12288 + ch] = r; r += v; }
            ws[SA2o + bb * 4097 + 4096] = r;
        } else if (tid == 193) {
            float r = 0.f;
            for (int ch = 0; ch < 64; ch++) { float v = smem[12352 + ch]; smem[12352 + ch] = r; r += v; }
            ws[SB2o + bb * 4097 + 4096] = r;
        }
        __syncthreads();
        for (int i = tid; i < 12288; i += 256) ws[Po + bb * 12288 + i] = smem[i];
        if (tid < 64)       ws[PSEAo + bb * 64 + tid] = smem[12288 + tid];
        else if (tid < 128) ws[PSAo + bb * 64 + tid - 64] = smem[12288 + tid];
    }
    gbar(&bar[3], 256);

    // ===== Phase E: write prefix table rows from register stash =====
    {
        float* part = smem;   // recompute (smem was clobbered for bid<4)
        part[(w * 3 + 0) * 64 + c] = s1;
        part[(w * 3 + 1) * 64 + c] = s2;
        part[(w * 3 + 2) * 64 + c] = s3;
        if (c == 0) { smem[768 + w] = sea_w; smem[772 + w] = sa_w; }
        __syncthreads();
        float r1 = ws[Po + ((b * 64 + t6) * 3 + 0) * 64 + c];
        float r2 = ws[Po + ((b * 64 + t6) * 3 + 1) * 64 + c];
        float r3 = ws[Po + ((b * 64 + t6) * 3 + 2) * 64 + c];
        float rsea = ws[PSEAo + b * 64 + t6], rsa = ws[PSAo + b * 64 + t6];
        for (int w2 = 0; w2 < w; w2++) {
            r1 += part[(w2 * 3 + 0) * 64 + c];
            r2 += part[(w2 * 3 + 1) * 64 + c];
            r3 += part[(w2 * 3 + 2) * 64 + c];
            rsea += smem[768 + w2]; rsa += smem[772 + w2];
        }
        size_t tb = (size_t)b * 4097 * 192;
#pragma unroll 4
        for (int k = 0; k < 16; k++) {
            size_t row = tb + (size_t)(r0 + k) * 192;
            ws[To + row + c]       = r1;
            ws[To + row + 64 + c]  = r2;
            ws[To + row + 128 + c] = r3;
            if (c == 0) {
                ws[SA2o + b * 4097 + r0 + k] = rsea;
                ws[SB2o + b * 4097 + r0 + k] = rsa;
                rsea += eas[k]; rsa += avs[k];
            }
            r1 += wvs[k]; r2 += wvs[k] * eas[k]; r3 += wvs[k] * avs[k];
        }
        if (t6 == 63 && w == 3) {
            size_t row = tb + (size_t)4096 * 192;
            ws[To + row + c] = r1; ws[To + row + 64 + c] = r2; ws[To + row + 128 + c] = r3;
        }
    }
    gbar(&bar[4], 256);

    // ===== Phase F: per-j denom + table gather -> output =====
    {
        float* L = smem;                         // [64][193]
        int*   tarr = (int*)(smem + 12352);
        float* djs = smem + 12416, *edjs = smem + 12480, *invden = smem + 12544;
        float* tot1 = smem + 12608, *tot3 = smem + 12672, *bgs = smem + 12736;
        const int* bst = (const int*)ws + BSTo;
        size_t tb = (size_t)b * 4097 * 192;
        int j0 = t6 * 64;
        if (tid < 64) {
            int j = j0 + tid;
            float dj = ws[Do + b * 4096 + j];
            float edj = expf(dj);
            int kb = bucket_of(-dj);
            int t = bst[b * NB + kb];
            float sa2  = ws[SA2o + b * 4097 + t];
            float sb2p = ws[SB2o + b * 4097 + t];
            float totA = ws[SB2o + b * 4097 + 4096];
            float den = 1.5f * ((totA - sb2p) + dj * (float)(4096 - t) - (float)t + edj * sa2);
            tarr[tid] = t; djs[tid] = dj; edjs[tid] = edj; invden[tid] = 1.0f / den;
        } else if (tid < 128) {
            int cc = tid - 64;
            tot1[cc] = ws[To + tb + (size_t)4096 * 192 + cc];
            bgs[cc] = bg[cc];
        } else if (tid < 192) {
            int cc = tid - 128;
            tot3[cc] = ws[To + tb + (size_t)4096 * 192 + 128 + cc];
        }
        __syncthreads();
        {
            int cc = tid & 63, jq = tid >> 6;
            for (int jj = jq; jj < 64; jj += 4) {
                size_t row = tb + (size_t)tarr[jj] * 192;
                L[jj * 193 + cc]       = ws[To + row + cc];
                L[jj * 193 + 64 + cc]  = ws[To + row + 64 + cc];
                L[jj * 193 + 128 + cc] = ws[To + row + 128 + cc];
            }
        }
        __syncthreads();
        {
            int jl = tid & 63, cq = tid >> 6;
            float dj = djs[jl], edj = edjs[jl], inv = invden[jl];
            for (int cc = cq; cc < 64; cc += 4) {
                float num = (tot3[cc] - L[jl * 193 + 128 + cc]) + dj * tot1[cc]
                          - (1.0f + dj) * L[jl * 193 + cc] + edj * L[jl * 193 + 64 + cc];
                out[((size_t)(b * 64 + cc)) * 4096 + j0 + jl] = num * inv + bgs[cc];
            }
        }
    }
}

extern "C" void kernel_launch(void* const* d_in, const int* in_sizes, int n_in,
                              void* d_out, int out_size, void* d_ws, size_t ws_size,
                              hipStream_t stream) {
    const float* x   = (const float*)d_in[0];
    const float* Wq  = (const float*)d_in[1];
    const float* bq  = (const float*)d_in[2];
    const float* Wk  = (const float*)d_in[3];
    const float* bk  = (const float*)d_in[4];
    const float* wcq = (const float*)d_in[5];
    const float* wck = (const float*)d_in[6];
    const float* Wv  = (const float*)d_in[7];
    const float* bv  = (const float*)d_in[8];
    const float* Wg  = (const float*)d_in[9];
    const float* bg  = (const float*)d_in[10];
    float* ws  = (float*)d_ws;
    float* out = (float*)d_out;

    hipMemsetAsync(d_ws, 0, 64, stream);   // zero grid-barrier counters
    k_fused<<<256, 256, 0, stream>>>(x, Wq, bq, Wk, bk, wcq, wck, Wv, bv, Wg, bg, ws, out);
}

// Round 4
// 207.778 us; speedup vs baseline: 2.0309x; 2.0309x over previous
//
#include <hip/hip_runtime.h>
#include <math.h>

#define NB 4096

// ---- workspace layout (float offsets) ----
#define BARo  0               // 16 ints: grid barrier counters (zeroed by memset)
#define Ao    16              // B*4096
#define Do    (Ao+16384)
#define VGo   (Do+16384)      // B*4096*64
#define ASo   (VGo+1048576)   // sorted a
#define PERMo (ASo+16384)     // int
#define BSTo  (PERMo+16384)   // int, bucket starts
#define Po    (BSTo+16384)    // chunk partials [b][64][3][64]
#define PSEAo (Po+49152)      // chunk scalar sum(e^a) [b][64]
#define PSAo  (PSEAo+256)     // chunk scalar sum(a)   [b][64]
#define SA2o  (PSAo+256)      // [b][4097]
#define SB2o  (SA2o+16388)    // [b][4097]
#define To    (SB2o+16388)    // tables [b][4097][3][64]

__device__ __forceinline__ int bucket_of(float v) {
    int k = (int)((v + 16.0f) * 128.0f);
    k = k < 0 ? 0 : k;
    k = k > (NB - 1) ? (NB - 1) : k;
    return k;
}

// Grid barrier: lane-0-only protocol, RELAXED spin (no per-poll invalidate),
// single release fence (L2 wb) before arrive, single acquire fence after.
__device__ __forceinline__ void gbar(int* bar, int n) {
    __syncthreads();
    if (threadIdx.x == 0) {
        __threadfence();   // release: drain + L2 writeback (agent scope)
        __hip_atomic_fetch_add(bar, 1, __ATOMIC_RELAXED, __HIP_MEMORY_SCOPE_AGENT);
        while (__hip_atomic_load(bar, __ATOMIC_RELAXED, __HIP_MEMORY_SCOPE_AGENT) < n)
            __builtin_amdgcn_s_sleep(2);
        __threadfence();   // acquire: invalidate L1/L2 before consuming
    }
    __syncthreads();
}

__global__ __launch_bounds__(256) void k_fused(
        const float* __restrict__ x,
        const float* __restrict__ Wq, const float* __restrict__ bq,
        const float* __restrict__ Wk, const float* __restrict__ bk,
        const float* __restrict__ wcq, const float* __restrict__ wck,
        const float* __restrict__ Wv, const float* __restrict__ bv,
        const float* __restrict__ Wg, const float* __restrict__ bg,
        float* __restrict__ ws, float* __restrict__ out) {
    __shared__ float smem[12800];       // 51.2 KB, overlaid per phase
    int tid = threadIdx.x;
    int bid = blockIdx.x;
    int b = bid >> 6, t6 = bid & 63;
    int* bar = (int*)ws + BARo;

    // ===== Phase A: weight prep (redundant per block) + projections =====
    {
        float* xt  = smem;              // [64][68]
        float* wt  = smem + 4352;       // [64][68]: wt[c][o] = Wvg[o][c]
        float* wqe = smem + 8704, *wke = smem + 8768, *bvg = smem + 8832, *misc = smem + 8896;
        if (tid < 64) {
            float s1 = 0.f, s2 = 0.f, s3 = 0.f;
            for (int o = 0; o < 16; o++) { s1 += wcq[o] * Wq[o * 64 + tid]; s2 += wck[o] * Wk[o * 64 + tid]; }
            for (int m = 0; m < 64; m++) s3 += Wg[tid * 64 + m] * bv[m];
            wqe[tid] = s1; wke[tid] = s2; bvg[tid] = s3;
        } else if (tid == 64) {
            float s = 0.f; for (int o = 0; o < 16; o++) s += wcq[o] * bq[o]; misc[0] = s;
        } else if (tid == 65) {
            float s = 0.f; for (int o = 0; o < 16; o++) s += wck[o] * bk[o]; misc[1] = s;
        }
        {
            int o = tid & 63, c0 = (tid >> 6) * 16;
            float acc[16];
#pragma unroll
            for (int k = 0; k < 16; k++) acc[k] = 0.f;
            for (int m = 0; m < 64; m++) {
                float wg = Wg[o * 64 + m];
                const float4* wv4 = (const float4*)(Wv + m * 64 + c0);
                float4 a0 = wv4[0], a1 = wv4[1], a2 = wv4[2], a3 = wv4[3];
                acc[0] += wg * a0.x; acc[1] += wg * a0.y; acc[2] += wg * a0.z; acc[3] += wg * a0.w;
                acc[4] += wg * a1.x; acc[5] += wg * a1.y; acc[6] += wg * a1.z; acc[7] += wg * a1.w;
                acc[8] += wg * a2.x; acc[9] += wg * a2.y; acc[10] += wg * a2.z; acc[11] += wg * a2.w;
                acc[12] += wg * a3.x; acc[13] += wg * a3.y; acc[14] += wg * a3.z; acc[15] += wg * a3.w;
            }
#pragma unroll
            for (int k = 0; k < 16; k++) wt[(c0 + k) * 68 + o] = acc[k];
        }
        const float* xb = x + (size_t)b * 64 * 4096;
        for (int idx = tid; idx < 4096; idx += 256) {
            int c = idx >> 6, nl = idx & 63;
            xt[c * 68 + nl] = xb[(size_t)c * 4096 + t6 * 64 + nl];
        }
        __syncthreads();
        if (tid < 64) {
            float s1 = misc[0], s2 = misc[1];
            for (int c = 0; c < 64; c++) {
                float xv = xt[c * 68 + tid];
                s1 += wqe[c] * xv; s2 += wke[c] * xv;
            }
            ws[Ao + b * 4096 + t6 * 64 + tid] = s1;
            ws[Do + b * 4096 + t6 * 64 + tid] = s2;
        }
        {
            int o = tid & 63, nl0 = (tid >> 6) * 16;
            float acc[16];
            float bo = bvg[o];
#pragma unroll
            for (int k = 0; k < 16; k++) acc[k] = bo;
            for (int c = 0; c < 64; c++) {
                float wv = wt[c * 68 + o];
                const float* xr = &xt[c * 68 + nl0];
#pragma unroll
                for (int k = 0; k < 16; k++) acc[k] += wv * xr[k];
            }
#pragma unroll
            for (int k = 0; k < 16; k++)
                ws[VGo + ((size_t)(b * 4096) + t6 * 64 + nl0 + k) * 64 + o] = acc[k];
        }
    }
    gbar(&bar[0], 256);

    // ===== Phase B: bucket quasi-sort of a (4 blocks, one per batch) =====
    if (bid < 4) {
        unsigned int* hist = (unsigned int*)smem;
        unsigned int* cnt  = hist + 4096;
        unsigned int* scanbuf = cnt + 4096;
        int bb = bid;
        const float* Ab = ws + Ao + bb * 4096;
        int* perm = (int*)ws + PERMo;
        int* bst  = (int*)ws + BSTo;
        for (int i = tid; i < NB; i += 256) { hist[i] = 0u; cnt[i] = 0u; }
        __syncthreads();
        for (int i = tid; i < 4096; i += 256) atomicAdd(&hist[bucket_of(Ab[i])], 1u);
        __syncthreads();
        unsigned int s = 0u; int base = tid * 16;
        for (int k = 0; k < 16; k++) s += hist[base + k];
        scanbuf[tid] = s;
        __syncthreads();
        for (int off = 1; off < 256; off <<= 1) {
            unsigned int v = scanbuf[tid];
            unsigned int u = (tid >= off) ? scanbuf[tid - off] : 0u;
            __syncthreads();
            scanbuf[tid] = v + u;
            __syncthreads();
        }
        unsigned int run = (tid > 0) ? scanbuf[tid - 1] : 0u;
        for (int k = 0; k < 16; k++) {
            unsigned int h = hist[base + k];
            hist[base + k] = run;
            bst[bb * NB + base + k] = (int)run;
            run += h;
        }
        __syncthreads();
        for (int i = tid; i < 4096; i += 256) {
            float av = Ab[i];
            int kb = bucket_of(av);
            unsigned int r = hist[kb] + atomicAdd(&cnt[kb], 1u);
            ws[ASo + bb * 4096 + r] = av;
            perm[bb * 4096 + r] = i;
        }
    }
    gbar(&bar[1], 256);

    // ===== Phase C: chunk partials; stash gathered values in registers =====
    int c = tid & 63, w = tid >> 6;
    int r0 = t6 * 64 + w * 16;
    float avs[16], eas[16], wvs[16];
    float s1 = 0.f, s2 = 0.f, s3 = 0.f, sea_w = 0.f, sa_w = 0.f;
    {
        const int* perm = (const int*)ws + PERMo;
#pragma unroll 4
        for (int k = 0; k < 16; k++) {
            int r = r0 + k;
            int p = perm[b * 4096 + r];
            float av = ws[ASo + b * 4096 + r];
            float ea = expf(av);
            float wv = ws[VGo + ((size_t)(b * 4096) + p) * 64 + c];
            avs[k] = av; eas[k] = ea; wvs[k] = wv;
            s1 += wv; s2 += wv * ea; s3 += wv * av;
            sea_w += ea; sa_w += av;
        }
        float* part = smem;
        part[(w * 3 + 0) * 64 + c] = s1;
        part[(w * 3 + 1) * 64 + c] = s2;
        part[(w * 3 + 2) * 64 + c] = s3;
        if (c == 0) { smem[768 + w] = sea_w; smem[772 + w] = sa_w; }
        __syncthreads();
        if (tid < 192) {
            int g = tid >> 6, cc = tid & 63;
            float s = part[(0 * 3 + g) * 64 + cc] + part[(1 * 3 + g) * 64 + cc]
                    + part[(2 * 3 + g) * 64 + cc] + part[(3 * 3 + g) * 64 + cc];
            ws[Po + (b * 64 + t6) * 192 + g * 64 + cc] = s;
        } else if (tid == 192) {
            ws[PSEAo + b * 64 + t6] = smem[768] + smem[769] + smem[770] + smem[771];
            ws[PSAo  + b * 64 + t6] = smem[772] + smem[773] + smem[774] + smem[775];
        }
    }
    gbar(&bar[2], 256);

    // ===== Phase E: in-block chunk-prefix + write table rows from stash =====
    {
        // smem still holds part[w][g][c] (0..767) and wave scalars (768..775)
        if (tid < 192) {
            float cp = 0.f;
            for (int ch = 0; ch < t6; ch++) cp += ws[Po + (b * 64 + ch) * 192 + tid];
            smem[776 + tid] = cp;          // chunk prefix, layout [g][c]
        } else {
            // wave 3: shfl-reduce scalar chunk prefixes
            float vea = (c < t6) ? ws[PSEAo + b * 64 + c] : 0.f;
            float va  = (c < t6) ? ws[PSAo  + b * 64 + c] : 0.f;
            for (int off = 32; off > 0; off >>= 1) {
                vea += __shfl_down(vea, off);
                va  += __shfl_down(va,  off);
            }
            if (c == 0) { smem[968] = vea; smem[969] = va; }
        }
        __syncthreads();
        float r1 = smem[776 + 0 * 64 + c];
        float r2 = smem[776 + 1 * 64 + c];
        float r3 = smem[776 + 2 * 64 + c];
        float rsea = smem[968], rsa = smem[969];
        float* part = smem;
        for (int w2 = 0; w2 < w; w2++) {
            r1 += part[(w2 * 3 + 0) * 64 + c];
            r2 += part[(w2 * 3 + 1) * 64 + c];
            r3 += part[(w2 * 3 + 2) * 64 + c];
            rsea += smem[768 + w2]; rsa += smem[772 + w2];
        }
        size_t tb = (size_t)b * 4097 * 192;
#pragma unroll 4
        for (int k = 0; k < 16; k++) {
            size_t row = tb + (size_t)(r0 + k) * 192;
            ws[To + row + c]       = r1;
            ws[To + row + 64 + c]  = r2;
            ws[To + row + 128 + c] = r3;
            if (c == 0) {
                ws[SA2o + b * 4097 + r0 + k] = rsea;
                ws[SB2o + b * 4097 + r0 + k] = rsa;
                rsea += eas[k]; rsa += avs[k];
            }
            r1 += wvs[k]; r2 += wvs[k] * eas[k]; r3 += wvs[k] * avs[k];
        }
        if (t6 == 63 && w == 3) {
            size_t row = tb + (size_t)4096 * 192;
            ws[To + row + c] = r1; ws[To + row + 64 + c] = r2; ws[To + row + 128 + c] = r3;
            if (c == 0) { ws[SA2o + b * 4097 + 4096] = rsea; ws[SB2o + b * 4097 + 4096] = rsa; }
        }
    }
    gbar(&bar[3], 256);

    // ===== Phase F: per-j denom + table gather -> output =====
    {
        float* L = smem;                         // [64][193]
        int*   tarr = (int*)(smem + 12352);
        float* djs = smem + 12416, *edjs = smem + 12480, *invden = smem + 12544;
        float* tot1 = smem + 12608, *tot3 = smem + 12672, *bgs = smem + 12736;
        const int* bst = (const int*)ws + BSTo;
        size_t tb = (size_t)b * 4097 * 192;
        int j0 = t6 * 64;
        if (tid < 64) {
            int j = j0 + tid;
            float dj = ws[Do + b * 4096 + j];
            float edj = expf(dj);
            int kb = bucket_of(-dj);
            int t = bst[b * NB + kb];
            float sa2  = ws[SA2o + b * 4097 + t];
            float sb2p = ws[SB2o + b * 4097 + t];
            float totA = ws[SB2o + b * 4097 + 4096];
            float den = 1.5f * ((totA - sb2p) + dj * (float)(4096 - t) - (float)t + edj * sa2);
            tarr[tid] = t; djs[tid] = dj; edjs[tid] = edj; invden[tid] = 1.0f / den;
        } else if (tid < 128) {
            int cc = tid - 64;
            tot1[cc] = ws[To + tb + (size_t)4096 * 192 + cc];
            bgs[cc] = bg[cc];
        } else if (tid < 192) {
            int cc = tid - 128;
            tot3[cc] = ws[To + tb + (size_t)4096 * 192 + 128 + cc];
        }
        __syncthreads();
        {
            int cc = tid & 63, jq = tid >> 6;
            for (int jj = jq; jj < 64; jj += 4) {
                size_t row = tb + (size_t)tarr[jj] * 192;
                L[jj * 193 + cc]       = ws[To + row + cc];
                L[jj * 193 + 64 + cc]  = ws[To + row + 64 + cc];
                L[jj * 193 + 128 + cc] = ws[To + row + 128 + cc];
            }
        }
        __syncthreads();
        {
            int jl = tid & 63, cq = tid >> 6;
            float dj = djs[jl], edj = edjs[jl], inv = invden[jl];
            for (int cc = cq; cc < 64; cc += 4) {
                float num = (tot3[cc] - L[jl * 193 + 128 + cc]) + dj * tot1[cc]
                          - (1.0f + dj) * L[jl * 193 + cc] + edj * L[jl * 193 + 64 + cc];
                out[((size_t)(b * 64 + cc)) * 4096 + j0 + jl] = num * inv + bgs[cc];
            }
        }
    }
}

extern "C" void kernel_launch(void* const* d_in, const int* in_sizes, int n_in,
                              void* d_out, int out_size, void* d_ws, size_t ws_size,
                              hipStream_t stream) {
    const float* x   = (const float*)d_in[0];
    const float* Wq  = (const float*)d_in[1];
    const float* bq  = (const float*)d_in[2];
    const float* Wk  = (const float*)d_in[3];
    const float* bk  = (const float*)d_in[4];
    const float* wcq = (const float*)d_in[5];
    const float* wck = (const float*)d_in[6];
    const float* Wv  = (const float*)d_in[7];
    const float* bv  = (const float*)d_in[8];
    const float* Wg  = (const float*)d_in[9];
    const float* bg  = (const float*)d_in[10];
    float* ws  = (float*)d_ws;
    float* out = (float*)d_out;

    hipMemsetAsync(d_ws, 0, 64, stream);   // zero grid-barrier counters
    k_fused<<<256, 256, 0, stream>>>(x, Wq, bq, Wk, bk, wcq, wck, Wv, bv, Wg, bg, ws, out);
}

// Round 5
// 184.934 us; speedup vs baseline: 2.2817x; 1.1235x over previous
//
#include <hip/hip_runtime.h>
#include <math.h>

#define NB 4096

// ---- workspace layout (float offsets) ----
#define BARo  0               // 16 ints: grid barrier counters (zeroed by memset)
#define Ao    16              // B*4096
#define Do    (Ao+16384)
#define VGo   (Do+16384)      // B*4096*64
#define ASo   (VGo+1048576)   // sorted a
#define PERMo (ASo+16384)     // int
#define BSTo  (PERMo+16384)   // int, bucket starts
#define Po    (BSTo+16384)    // chunk partials [b][64][3][64]
#define PSEAo (Po+49152)      // chunk scalar sum(e^a) [b][64]
#define PSAo  (PSEAo+256)     // chunk scalar sum(a)   [b][64]
#define SA2o  (PSAo+256)      // [b][4097]
#define SB2o  (SA2o+16388)    // [b][4097]
#define To    (SB2o+16388)    // tables [b][4097][3][64]

// Device-coherent (agent-scope, cache-bypassing) scalar access helpers.
// All cross-block data goes through these => grid barriers need NO cache
// maintenance (no buffer_wbl2 / buffer_inv), which was ~105us of R4's 140us.
__device__ __forceinline__ float gld(const float* p) {
    return __hip_atomic_load(p, __ATOMIC_RELAXED, __HIP_MEMORY_SCOPE_AGENT);
}
__device__ __forceinline__ void gst(float* p, float v) {
    __hip_atomic_store(p, v, __ATOMIC_RELAXED, __HIP_MEMORY_SCOPE_AGENT);
}
__device__ __forceinline__ int gldi(const int* p) {
    return __hip_atomic_load(p, __ATOMIC_RELAXED, __HIP_MEMORY_SCOPE_AGENT);
}
__device__ __forceinline__ void gsti(int* p, int v) {
    __hip_atomic_store(p, v, __ATOMIC_RELAXED, __HIP_MEMORY_SCOPE_AGENT);
}

__device__ __forceinline__ int bucket_of(float v) {
    int k = (int)((v + 16.0f) * 128.0f);
    k = k < 0 ? 0 : k;
    k = k > (NB - 1) ? (NB - 1) : k;
    return k;
}

// Fence-free rendezvous: __syncthreads() drains each wave's vmcnt (compiler
// emits s_waitcnt before s_barrier), so all sc-coherent stores are globally
// visible before lane 0 arrives. No wbl2/inv needed.
__device__ __forceinline__ void gbar(int* bar, int n) {
    __syncthreads();
    if (threadIdx.x == 0) {
        __hip_atomic_fetch_add(bar, 1, __ATOMIC_RELAXED, __HIP_MEMORY_SCOPE_AGENT);
        while (__hip_atomic_load(bar, __ATOMIC_RELAXED, __HIP_MEMORY_SCOPE_AGENT) < n)
            __builtin_amdgcn_s_sleep(2);
    }
    __syncthreads();
}

__global__ __launch_bounds__(256) void k_fused(
        const float* __restrict__ x,
        const float* __restrict__ Wq, const float* __restrict__ bq,
        const float* __restrict__ Wk, const float* __restrict__ bk,
        const float* __restrict__ wcq, const float* __restrict__ wck,
        const float* __restrict__ Wv, const float* __restrict__ bv,
        const float* __restrict__ Wg, const float* __restrict__ bg,
        float* __restrict__ ws, float* __restrict__ out) {
    __shared__ float smem[12800];       // 51.2 KB, overlaid per phase
    int tid = threadIdx.x;
    int bid = blockIdx.x;
    int b = bid >> 6, t6 = bid & 63;
    int* bar = (int*)ws + BARo;

    // ===== Phase A: weight prep (redundant per block) + projections =====
    {
        float* xt  = smem;              // [64][68]
        float* wt  = smem + 4352;       // [64][68]: wt[c][o] = Wvg[o][c]
        float* wqe = smem + 8704, *wke = smem + 8768, *bvg = smem + 8832, *misc = smem + 8896;
        if (tid < 64) {
            float s1 = 0.f, s2 = 0.f, s3 = 0.f;
            for (int o = 0; o < 16; o++) { s1 += wcq[o] * Wq[o * 64 + tid]; s2 += wck[o] * Wk[o * 64 + tid]; }
            for (int m = 0; m < 64; m++) s3 += Wg[tid * 64 + m] * bv[m];
            wqe[tid] = s1; wke[tid] = s2; bvg[tid] = s3;
        } else if (tid == 64) {
            float s = 0.f; for (int o = 0; o < 16; o++) s += wcq[o] * bq[o]; misc[0] = s;
        } else if (tid == 65) {
            float s = 0.f; for (int o = 0; o < 16; o++) s += wck[o] * bk[o]; misc[1] = s;
        }
        {
            int o = tid & 63, c0 = (tid >> 6) * 16;
            float acc[16];
#pragma unroll
            for (int k = 0; k < 16; k++) acc[k] = 0.f;
            for (int m = 0; m < 64; m++) {
                float wg = Wg[o * 64 + m];
                const float4* wv4 = (const float4*)(Wv + m * 64 + c0);
                float4 a0 = wv4[0], a1 = wv4[1], a2 = wv4[2], a3 = wv4[3];
                acc[0] += wg * a0.x; acc[1] += wg * a0.y; acc[2] += wg * a0.z; acc[3] += wg * a0.w;
                acc[4] += wg * a1.x; acc[5] += wg * a1.y; acc[6] += wg * a1.z; acc[7] += wg * a1.w;
                acc[8] += wg * a2.x; acc[9] += wg * a2.y; acc[10] += wg * a2.z; acc[11] += wg * a2.w;
                acc[12] += wg * a3.x; acc[13] += wg * a3.y; acc[14] += wg * a3.z; acc[15] += wg * a3.w;
            }
#pragma unroll
            for (int k = 0; k < 16; k++) wt[(c0 + k) * 68 + o] = acc[k];
        }
        const float* xb = x + (size_t)b * 64 * 4096;
        for (int idx = tid; idx < 4096; idx += 256) {
            int c = idx >> 6, nl = idx & 63;
            xt[c * 68 + nl] = xb[(size_t)c * 4096 + t6 * 64 + nl];
        }
        __syncthreads();
        if (tid < 64) {
            float s1 = misc[0], s2 = misc[1];
            for (int c = 0; c < 64; c++) {
                float xv = xt[c * 68 + tid];
                s1 += wqe[c] * xv; s2 += wke[c] * xv;
            }
            gst(&ws[Ao + b * 4096 + t6 * 64 + tid], s1);   // cross-block (phase B)
            ws[Do + b * 4096 + t6 * 64 + tid] = s2;        // block-local (phase F, same block)
        }
        {
            int o = tid & 63, nl0 = (tid >> 6) * 16;
            float acc[16];
            float bo = bvg[o];
#pragma unroll
            for (int k = 0; k < 16; k++) acc[k] = bo;
            for (int c = 0; c < 64; c++) {
                float wv = wt[c * 68 + o];
                const float* xr = &xt[c * 68 + nl0];
#pragma unroll
                for (int k = 0; k < 16; k++) acc[k] += wv * xr[k];
            }
#pragma unroll
            for (int k = 0; k < 16; k++)
                gst(&ws[VGo + ((size_t)(b * 4096) + t6 * 64 + nl0 + k) * 64 + o], acc[k]);
        }
    }
    gbar(&bar[0], 256);

    // ===== Phase B: bucket quasi-sort of a (4 blocks, one per batch) =====
    if (bid < 4) {
        unsigned int* hist = (unsigned int*)smem;
        unsigned int* cnt  = hist + 4096;
        unsigned int* scanbuf = cnt + 4096;
        int bb = bid;
        const float* Ab = ws + Ao + bb * 4096;
        int* perm = (int*)ws + PERMo;
        int* bst  = (int*)ws + BSTo;
        for (int i = tid; i < NB; i += 256) { hist[i] = 0u; cnt[i] = 0u; }
        __syncthreads();
        for (int i = tid; i < 4096; i += 256) atomicAdd(&hist[bucket_of(gld(&Ab[i]))], 1u);
        __syncthreads();
        unsigned int s = 0u; int base = tid * 16;
        for (int k = 0; k < 16; k++) s += hist[base + k];
        scanbuf[tid] = s;
        __syncthreads();
        for (int off = 1; off < 256; off <<= 1) {
            unsigned int v = scanbuf[tid];
            unsigned int u = (tid >= off) ? scanbuf[tid - off] : 0u;
            __syncthreads();
            scanbuf[tid] = v + u;
            __syncthreads();
        }
        unsigned int run = (tid > 0) ? scanbuf[tid - 1] : 0u;
        for (int k = 0; k < 16; k++) {
            unsigned int h = hist[base + k];
            hist[base + k] = run;
            gsti(&bst[bb * NB + base + k], (int)run);
            run += h;
        }
        __syncthreads();
        for (int i = tid; i < 4096; i += 256) {
            float av = gld(&Ab[i]);
            int kb = bucket_of(av);
            unsigned int r = hist[kb] + atomicAdd(&cnt[kb], 1u);
            gst(&ws[ASo + bb * 4096 + r], av);
            gsti(&perm[bb * 4096 + r], (int)i);
        }
    }
    gbar(&bar[1], 256);

    // ===== Phase C: chunk partials; stash gathered values in registers =====
    int c = tid & 63, w = tid >> 6;
    int r0 = t6 * 64 + w * 16;
    float avs[16], eas[16], wvs[16];
    float s1 = 0.f, s2 = 0.f, s3 = 0.f, sea_w = 0.f, sa_w = 0.f;
    {
        const int* perm = (const int*)ws + PERMo;
#pragma unroll 4
        for (int k = 0; k < 16; k++) {
            int r = r0 + k;
            int p = gldi(&perm[b * 4096 + r]);
            float av = gld(&ws[ASo + b * 4096 + r]);
            float ea = expf(av);
            float wv = gld(&ws[VGo + ((size_t)(b * 4096) + p) * 64 + c]);
            avs[k] = av; eas[k] = ea; wvs[k] = wv;
            s1 += wv; s2 += wv * ea; s3 += wv * av;
            sea_w += ea; sa_w += av;
        }
        float* part = smem;
        part[(w * 3 + 0) * 64 + c] = s1;
        part[(w * 3 + 1) * 64 + c] = s2;
        part[(w * 3 + 2) * 64 + c] = s3;
        if (c == 0) { smem[768 + w] = sea_w; smem[772 + w] = sa_w; }
        __syncthreads();
        if (tid < 192) {
            int g = tid >> 6, cc = tid & 63;
            float s = part[(0 * 3 + g) * 64 + cc] + part[(1 * 3 + g) * 64 + cc]
                    + part[(2 * 3 + g) * 64 + cc] + part[(3 * 3 + g) * 64 + cc];
            gst(&ws[Po + (b * 64 + t6) * 192 + g * 64 + cc], s);
        } else if (tid == 192) {
            gst(&ws[PSEAo + b * 64 + t6], smem[768] + smem[769] + smem[770] + smem[771]);
            gst(&ws[PSAo  + b * 64 + t6], smem[772] + smem[773] + smem[774] + smem[775]);
        }
    }
    gbar(&bar[2], 256);

    // ===== Phase E: in-block chunk-prefix + write table rows from stash =====
    {
        // smem still holds part[w][g][c] (0..767) and wave scalars (768..775)
        if (tid < 192) {
            float cp = 0.f;
            for (int ch = 0; ch < t6; ch++) cp += gld(&ws[Po + (b * 64 + ch) * 192 + tid]);
            smem[776 + tid] = cp;          // chunk prefix, layout [g][c]
        } else {
            // wave 3: shfl-reduce scalar chunk prefixes
            float vea = (c < t6) ? gld(&ws[PSEAo + b * 64 + c]) : 0.f;
            float va  = (c < t6) ? gld(&ws[PSAo  + b * 64 + c]) : 0.f;
            for (int off = 32; off > 0; off >>= 1) {
                vea += __shfl_down(vea, off);
                va  += __shfl_down(va,  off);
            }
            if (c == 0) { smem[968] = vea; smem[969] = va; }
        }
        __syncthreads();
        float r1 = smem[776 + 0 * 64 + c];
        float r2 = smem[776 + 1 * 64 + c];
        float r3 = smem[776 + 2 * 64 + c];
        float rsea = smem[968], rsa = smem[969];
        float* part = smem;
        for (int w2 = 0; w2 < w; w2++) {
            r1 += part[(w2 * 3 + 0) * 64 + c];
            r2 += part[(w2 * 3 + 1) * 64 + c];
            r3 += part[(w2 * 3 + 2) * 64 + c];
            rsea += smem[768 + w2]; rsa += smem[772 + w2];
        }
        size_t tb = (size_t)b * 4097 * 192;
#pragma unroll 4
        for (int k = 0; k < 16; k++) {
            size_t row = tb + (size_t)(r0 + k) * 192;
            gst(&ws[To + row + c], r1);
            gst(&ws[To + row + 64 + c], r2);
            gst(&ws[To + row + 128 + c], r3);
            if (c == 0) {
                gst(&ws[SA2o + b * 4097 + r0 + k], rsea);
                gst(&ws[SB2o + b * 4097 + r0 + k], rsa);
                rsea += eas[k]; rsa += avs[k];
            }
            r1 += wvs[k]; r2 += wvs[k] * eas[k]; r3 += wvs[k] * avs[k];
        }
        if (t6 == 63 && w == 3) {
            size_t row = tb + (size_t)4096 * 192;
            gst(&ws[To + row + c], r1);
            gst(&ws[To + row + 64 + c], r2);
            gst(&ws[To + row + 128 + c], r3);
            if (c == 0) { gst(&ws[SA2o + b * 4097 + 4096], rsea); gst(&ws[SB2o + b * 4097 + 4096], rsa); }
        }
    }
    gbar(&bar[3], 256);

    // ===== Phase F: per-j denom + table gather -> output =====
    {
        float* L = smem;                         // [64][193]
        int*   tarr = (int*)(smem + 12352);
        float* djs = smem + 12416, *edjs = smem + 12480, *invden = smem + 12544;
        float* tot1 = smem + 12608, *tot3 = smem + 12672, *bgs = smem + 12736;
        const int* bst = (const int*)ws + BSTo;
        size_t tb = (size_t)b * 4097 * 192;
        int j0 = t6 * 64;
        if (tid < 64) {
            int j = j0 + tid;
            float dj = ws[Do + b * 4096 + j];
            float edj = expf(dj);
            int kb = bucket_of(-dj);
            int t = gldi(&bst[b * NB + kb]);
            float sa2  = gld(&ws[SA2o + b * 4097 + t]);
            float sb2p = gld(&ws[SB2o + b * 4097 + t]);
            float totA = gld(&ws[SB2o + b * 4097 + 4096]);
            float den = 1.5f * ((totA - sb2p) + dj * (float)(4096 - t) - (float)t + edj * sa2);
            tarr[tid] = t; djs[tid] = dj; edjs[tid] = edj; invden[tid] = 1.0f / den;
        } else if (tid < 128) {
            int cc = tid - 64;
            tot1[cc] = gld(&ws[To + tb + (size_t)4096 * 192 + cc]);
            bgs[cc] = bg[cc];
        } else if (tid < 192) {
            int cc = tid - 128;
            tot3[cc] = gld(&ws[To + tb + (size_t)4096 * 192 + 128 + cc]);
        }
        __syncthreads();
        {
            int cc = tid & 63, jq = tid >> 6;
            for (int jj = jq; jj < 64; jj += 4) {
                size_t row = tb + (size_t)tarr[jj] * 192;
                L[jj * 193 + cc]       = gld(&ws[To + row + cc]);
                L[jj * 193 + 64 + cc]  = gld(&ws[To + row + 64 + cc]);
                L[jj * 193 + 128 + cc] = gld(&ws[To + row + 128 + cc]);
            }
        }
        __syncthreads();
        {
            int jl = tid & 63, cq = tid >> 6;
            float dj = djs[jl], edj = edjs[jl], inv = invden[jl];
            for (int cc = cq; cc < 64; cc += 4) {
                float num = (tot3[cc] - L[jl * 193 + 128 + cc]) + dj * tot1[cc]
                          - (1.0f + dj) * L[jl * 193 + cc] + edj * L[jl * 193 + 64 + cc];
                out[((size_t)(b * 64 + cc)) * 4096 + j0 + jl] = num * inv + bgs[cc];
            }
        }
    }
}

extern "C" void kernel_launch(void* const* d_in, const int* in_sizes, int n_in,
                              void* d_out, int out_size, void* d_ws, size_t ws_size,
                              hipStream_t stream) {
    const float* x   = (const float*)d_in[0];
    const float* Wq  = (const float*)d_in[1];
    const float* bq  = (const float*)d_in[2];
    const float* Wk  = (const float*)d_in[3];
    const float* bk  = (const float*)d_in[4];
    const float* wcq = (const float*)d_in[5];
    const float* wck = (const float*)d_in[6];
    const float* Wv  = (const float*)d_in[7];
    const float* bv  = (const float*)d_in[8];
    const float* Wg  = (const float*)d_in[9];
    const float* bg  = (const float*)d_in[10];
    float* ws  = (float*)d_ws;
    float* out = (float*)d_out;

    hipMemsetAsync(d_ws, 0, 64, stream);   // zero grid-barrier counters
    k_fused<<<256, 256, 0, stream>>>(x, Wq, bq, Wk, bk, wcq, wck, Wv, bv, Wg, bg, ws, out);
}

// Round 6
// 157.194 us; speedup vs baseline: 2.6844x; 1.1765x over previous
//
#include <hip/hip_runtime.h>
#include <math.h>

#define NB 4096

// ---- workspace layout (float offsets) ----
#define BARo  0               // 16 ints: grid barrier counters (zeroed by memset)
#define GHo   16              // 4*4096 ints: global histogram (zeroed by memset)
#define Ao    16400           // B*4096
#define Do    32784
#define VGo   49168           // B*4096*64
#define ASo   1097744         // sorted a
#define PERMo 1114128         // int
#define BSTo  1130512         // int, bucket starts
#define Po    1146896         // chunk partials [b][64ch][192gc]
#define PSEAo 1196048         // chunk scalar sum(e^a) [b][64]
#define PSAo  1196304         // chunk scalar sum(a)   [b][64]
#define SA2o  1196560         // [b][4097]
#define SB2o  1212948         // [b][4097]
#define To    1229336         // tables [b][4097][3][64]

// Device-coherent (agent-scope, cache-bypassing) scalar access helpers.
__device__ __forceinline__ float gld(const float* p) {
    return __hip_atomic_load(p, __ATOMIC_RELAXED, __HIP_MEMORY_SCOPE_AGENT);
}
__device__ __forceinline__ void gst(float* p, float v) {
    __hip_atomic_store(p, v, __ATOMIC_RELAXED, __HIP_MEMORY_SCOPE_AGENT);
}
__device__ __forceinline__ int gldi(const int* p) {
    return __hip_atomic_load(p, __ATOMIC_RELAXED, __HIP_MEMORY_SCOPE_AGENT);
}
__device__ __forceinline__ void gsti(int* p, int v) {
    __hip_atomic_store(p, v, __ATOMIC_RELAXED, __HIP_MEMORY_SCOPE_AGENT);
}

__device__ __forceinline__ int bucket_of(float v) {
    int k = (int)((v + 16.0f) * 128.0f);
    k = k < 0 ? 0 : k;
    k = k > (NB - 1) ? (NB - 1) : k;
    return k;
}

// Fence-free rendezvous (validated R5): sc-coherent data needs no wbl2/inv.
__device__ __forceinline__ void gbar(int* bar, int n) {
    __syncthreads();
    if (threadIdx.x == 0) {
        __hip_atomic_fetch_add(bar, 1, __ATOMIC_RELAXED, __HIP_MEMORY_SCOPE_AGENT);
        while (__hip_atomic_load(bar, __ATOMIC_RELAXED, __HIP_MEMORY_SCOPE_AGENT) < n)
            __builtin_amdgcn_s_sleep(2);
    }
    __syncthreads();
}

__global__ __launch_bounds__(256, 1) void k_fused(
        const float* __restrict__ x,
        const float* __restrict__ Wq, const float* __restrict__ bq,
        const float* __restrict__ Wk, const float* __restrict__ bk,
        const float* __restrict__ wcq, const float* __restrict__ wck,
        const float* __restrict__ Wv, const float* __restrict__ bv,
        const float* __restrict__ Wg, const float* __restrict__ bg,
        float* __restrict__ ws, float* __restrict__ out) {
    __shared__ float smem[15872];       // 63.5 KB; 1-2 blocks/CU, grid=256 on 256 CUs
    int tid = threadIdx.x;
    int bid = blockIdx.x;
    int b = bid >> 6, t6 = bid & 63;
    int* bar = (int*)ws + BARo;
    int* gh  = (int*)ws + GHo;

    // partL region survives C -> E (E's bulk load only touches [0..12609])
    float* partL = smem + 15000;        // [4][3][64] = 768
    float* wsc   = smem + 15776;        // [8]

    // ===== Phase A: weight prep (redundant per block) + projections + hist =====
    {
        float* xt  = smem;              // [64][68]
        float* wt  = smem + 4352;       // [64][68]: wt[c][o] = Wvg[o][c]
        float* wqe = smem + 8704, *wke = smem + 8768, *bvg = smem + 8832, *misc = smem + 8896;
        if (tid < 64) {
            float s1 = 0.f, s2 = 0.f, s3 = 0.f;
            for (int o = 0; o < 16; o++) { s1 += wcq[o] * Wq[o * 64 + tid]; s2 += wck[o] * Wk[o * 64 + tid]; }
            for (int m = 0; m < 64; m++) s3 += Wg[tid * 64 + m] * bv[m];
            wqe[tid] = s1; wke[tid] = s2; bvg[tid] = s3;
        } else if (tid == 64) {
            float s = 0.f; for (int o = 0; o < 16; o++) s += wcq[o] * bq[o]; misc[0] = s;
        } else if (tid == 65) {
            float s = 0.f; for (int o = 0; o < 16; o++) s += wck[o] * bk[o]; misc[1] = s;
        }
        {
            int o = tid & 63, c0 = (tid >> 6) * 16;
            float acc[16];
#pragma unroll
            for (int k = 0; k < 16; k++) acc[k] = 0.f;
            for (int m = 0; m < 64; m++) {
                float wg = Wg[o * 64 + m];
                const float4* wv4 = (const float4*)(Wv + m * 64 + c0);
                float4 a0 = wv4[0], a1 = wv4[1], a2 = wv4[2], a3 = wv4[3];
                acc[0] += wg * a0.x; acc[1] += wg * a0.y; acc[2] += wg * a0.z; acc[3] += wg * a0.w;
                acc[4] += wg * a1.x; acc[5] += wg * a1.y; acc[6] += wg * a1.z; acc[7] += wg * a1.w;
                acc[8] += wg * a2.x; acc[9] += wg * a2.y; acc[10] += wg * a2.z; acc[11] += wg * a2.w;
                acc[12] += wg * a3.x; acc[13] += wg * a3.y; acc[14] += wg * a3.z; acc[15] += wg * a3.w;
            }
#pragma unroll
            for (int k = 0; k < 16; k++) wt[(c0 + k) * 68 + o] = acc[k];
        }
        const float* xb = x + (size_t)b * 64 * 4096;
        for (int idx = tid; idx < 4096; idx += 256) {
            int c = idx >> 6, nl = idx & 63;
            xt[c * 68 + nl] = xb[(size_t)c * 4096 + t6 * 64 + nl];
        }
        __syncthreads();
        if (tid < 64) {
            float s1 = misc[0], s2 = misc[1];
            for (int c = 0; c < 64; c++) {
                float xv = xt[c * 68 + tid];
                s1 += wqe[c] * xv; s2 += wke[c] * xv;
            }
            gst(&ws[Ao + b * 4096 + t6 * 64 + tid], s1);   // cross-block (phase B)
            ws[Do + b * 4096 + t6 * 64 + tid] = s2;        // block-local (phase F)
            atomicAdd(&gh[b * 4096 + bucket_of(s1)], 1);   // fused histogram
        }
        {
            int o = tid & 63, nl0 = (tid >> 6) * 16;
            float acc[16];
            float bo = bvg[o];
#pragma unroll
            for (int k = 0; k < 16; k++) acc[k] = bo;
            for (int c = 0; c < 64; c++) {
                float wv = wt[c * 68 + o];
                const float* xr = &xt[c * 68 + nl0];
#pragma unroll
                for (int k = 0; k < 16; k++) acc[k] += wv * xr[k];
            }
#pragma unroll
            for (int k = 0; k < 16; k++)
                gst(&ws[VGo + ((size_t)(b * 4096) + t6 * 64 + nl0 + k) * 64 + o], acc[k]);
        }
    }
    gbar(&bar[0], 256);

    // ===== Phase B: scan histogram + scatter (4 blocks, one per batch) =====
    if (bid < 4) {
        unsigned int* hist = (unsigned int*)smem;
        unsigned int* cnt  = hist + 4096;
        unsigned int* scanbuf = cnt + 4096;
        int bb = bid;
        const float* Ab = ws + Ao + bb * 4096;
        int* perm = (int*)ws + PERMo;
        int* bst  = (int*)ws + BSTo;
#pragma unroll 4
        for (int i = tid; i < NB; i += 256) {
            hist[i] = (unsigned int)gldi(&gh[bb * 4096 + i]);
            cnt[i] = 0u;
        }
        __syncthreads();
        unsigned int s = 0u; int base = tid * 16;
        for (int k = 0; k < 16; k++) s += hist[base + k];
        scanbuf[tid] = s;
        __syncthreads();
        for (int off = 1; off < 256; off <<= 1) {
            unsigned int v = scanbuf[tid];
            unsigned int u = (tid >= off) ? scanbuf[tid - off] : 0u;
            __syncthreads();
            scanbuf[tid] = v + u;
            __syncthreads();
        }
        unsigned int run = (tid > 0) ? scanbuf[tid - 1] : 0u;
        for (int k = 0; k < 16; k++) {
            unsigned int h = hist[base + k];
            hist[base + k] = run;
            gsti(&bst[bb * NB + base + k], (int)run);
            run += h;
        }
        __syncthreads();
#pragma unroll 4
        for (int i = tid; i < 4096; i += 256) {
            float av = gld(&Ab[i]);
            int kb = bucket_of(av);
            unsigned int r = hist[kb] + atomicAdd(&cnt[kb], 1u);
            gst(&ws[ASo + bb * 4096 + r], av);
            gsti(&perm[bb * 4096 + r], (int)i);
        }
    }
    gbar(&bar[1], 256);

    // ===== Phase C: chunk partials, MLP-friendly flat load passes =====
    int c = tid & 63, w = tid >> 6;
    int r0 = t6 * 64 + w * 16;
    float avs[16], eas[16], wvs[16];
    float s1 = 0.f, s2 = 0.f, s3 = 0.f, sea_w = 0.f, sa_w = 0.f;
    {
        const int* perm = (const int*)ws + PERMo;
        int pk[16];
#pragma unroll
        for (int k = 0; k < 16; k++) pk[k] = gldi(&perm[b * 4096 + r0 + k]);
#pragma unroll
        for (int k = 0; k < 16; k++) avs[k] = gld(&ws[ASo + b * 4096 + r0 + k]);
#pragma unroll
        for (int k = 0; k < 16; k++) wvs[k] = gld(&ws[VGo + ((size_t)(b * 4096) + pk[k]) * 64 + c]);
#pragma unroll
        for (int k = 0; k < 16; k++) {
            float ea = expf(avs[k]);
            eas[k] = ea;
            s1 += wvs[k]; s2 += wvs[k] * ea; s3 += wvs[k] * avs[k];
            sea_w += ea; sa_w += avs[k];
        }
        partL[(w * 3 + 0) * 64 + c] = s1;
        partL[(w * 3 + 1) * 64 + c] = s2;
        partL[(w * 3 + 2) * 64 + c] = s3;
        if (c == 0) { wsc[w] = sea_w; wsc[4 + w] = sa_w; }
        __syncthreads();
        if (tid < 192) {
            int g = tid >> 6, cc = tid & 63;
            float s = partL[(0 * 3 + g) * 64 + cc] + partL[(1 * 3 + g) * 64 + cc]
                    + partL[(2 * 3 + g) * 64 + cc] + partL[(3 * 3 + g) * 64 + cc];
            gst(&ws[Po + (b * 64 + t6) * 192 + tid], s);
        } else if (tid == 192) {
            gst(&ws[PSEAo + b * 64 + t6], wsc[0] + wsc[1] + wsc[2] + wsc[3]);
            gst(&ws[PSAo  + b * 64 + t6], wsc[4] + wsc[5] + wsc[6] + wsc[7]);
        }
    }
    gbar(&bar[2], 256);

    // ===== Phase E: bulk-load chunk partials, LDS prefix, write table rows =====
    {
        // bulk load Po[b] (12288 floats) into smem[0..12287] — 48 indep loads/thread
#pragma unroll 8
        for (int i = tid; i < 12288; i += 256) smem[i] = gld(&ws[Po + b * 12288 + i]);
        float* scEA = smem + 12288;     // [64]
        float* scA  = smem + 12352;     // [64]
        float* cpL  = smem + 12416;     // [192]
        if (tid < 64)       scEA[tid] = gld(&ws[PSEAo + b * 64 + tid]);
        else if (tid < 128) scA[tid - 64] = gld(&ws[PSAo + b * 64 + tid - 64]);
        __syncthreads();
        if (tid < 192) {
            float cp = 0.f;
            for (int ch = 0; ch < t6; ch++) cp += smem[ch * 192 + tid];
            cpL[tid] = cp;
        } else if (tid == 192) {
            float r = 0.f; for (int ch = 0; ch < t6; ch++) r += scEA[ch];
            smem[12608] = r;
        } else if (tid == 193) {
            float r = 0.f; for (int ch = 0; ch < t6; ch++) r += scA[ch];
            smem[12609] = r;
        }
        __syncthreads();
        float r1 = cpL[c], r2 = cpL[64 + c], r3 = cpL[128 + c];
        float rsea = smem[12608], rsa = smem[12609];
        for (int w2 = 0; w2 < w; w2++) {
            r1 += partL[(w2 * 3 + 0) * 64 + c];
            r2 += partL[(w2 * 3 + 1) * 64 + c];
            r3 += partL[(w2 * 3 + 2) * 64 + c];
            rsea += wsc[w2]; rsa += wsc[4 + w2];
        }
        size_t tb = (size_t)b * 4097 * 192;
#pragma unroll 4
        for (int k = 0; k < 16; k++) {
            size_t row = tb + (size_t)(r0 + k) * 192;
            gst(&ws[To + row + c], r1);
            gst(&ws[To + row + 64 + c], r2);
            gst(&ws[To + row + 128 + c], r3);
            if (c == 0) {
                gst(&ws[SA2o + b * 4097 + r0 + k], rsea);
                gst(&ws[SB2o + b * 4097 + r0 + k], rsa);
                rsea += eas[k]; rsa += avs[k];
            }
            r1 += wvs[k]; r2 += wvs[k] * eas[k]; r3 += wvs[k] * avs[k];
        }
        if (t6 == 63 && w == 3) {
            size_t row = tb + (size_t)4096 * 192;
            gst(&ws[To + row + c], r1);
            gst(&ws[To + row + 64 + c], r2);
            gst(&ws[To + row + 128 + c], r3);
            if (c == 0) { gst(&ws[SA2o + b * 4097 + 4096], rsea); gst(&ws[SB2o + b * 4097 + 4096], rsa); }
        }
    }
    gbar(&bar[3], 256);

    // ===== Phase F: per-j denom + register-prefetched table gather -> out =====
    {
        float* L = smem;                         // [64][193]
        int*   tarr = (int*)(smem + 12352);
        float* djs = smem + 12416, *edjs = smem + 12480, *invden = smem + 12544;
        float* tot1 = smem + 12608, *tot3 = smem + 12672, *bgs = smem + 12736;
        const int* bst = (const int*)ws + BSTo;
        size_t tb = (size_t)b * 4097 * 192;
        int j0 = t6 * 64;
        if (tid < 64) {
            int j = j0 + tid;
            float dj = ws[Do + b * 4096 + j];
            float edj = expf(dj);
            int kb = bucket_of(-dj);
            int t = gldi(&bst[b * NB + kb]);
            float sa2  = gld(&ws[SA2o + b * 4097 + t]);
            float sb2p = gld(&ws[SB2o + b * 4097 + t]);
            float totA = gld(&ws[SB2o + b * 4097 + 4096]);
            float den = 1.5f * ((totA - sb2p) + dj * (float)(4096 - t) - (float)t + edj * sa2);
            tarr[tid] = t; djs[tid] = dj; edjs[tid] = edj; invden[tid] = 1.0f / den;
        } else if (tid < 128) {
            int cc = tid - 64;
            tot1[cc] = gld(&ws[To + tb + (size_t)4096 * 192 + cc]);
            bgs[cc] = bg[cc];
        } else if (tid < 192) {
            int cc = tid - 128;
            tot3[cc] = gld(&ws[To + tb + (size_t)4096 * 192 + 128 + cc]);
        }
        __syncthreads();
        {
            int cc = tid & 63, jq = tid >> 6;
            float f1[16], f2[16], f3[16];
#pragma unroll
            for (int u = 0; u < 16; u++) {
                int jj = u * 4 + jq;
                size_t row = tb + (size_t)tarr[jj] * 192;
                f1[u] = gld(&ws[To + row + cc]);
                f2[u] = gld(&ws[To + row + 64 + cc]);
                f3[u] = gld(&ws[To + row + 128 + cc]);
            }
#pragma unroll
            for (int u = 0; u < 16; u++) {
                int jj = u * 4 + jq;
                L[jj * 193 + cc]       = f1[u];
                L[jj * 193 + 64 + cc]  = f2[u];
                L[jj * 193 + 128 + cc] = f3[u];
            }
        }
        __syncthreads();
        {
            int jl = tid & 63, cq = tid >> 6;
            float dj = djs[jl], edj = edjs[jl], inv = invden[jl];
            for (int cc = cq; cc < 64; cc += 4) {
                float num = (tot3[cc] - L[jl * 193 + 128 + cc]) + dj * tot1[cc]
                          - (1.0f + dj) * L[jl * 193 + cc] + edj * L[jl * 193 + 64 + cc];
                out[((size_t)(b * 64 + cc)) * 4096 + j0 + jl] = num * inv + bgs[cc];
            }
        }
    }
}

extern "C" void kernel_launch(void* const* d_in, const int* in_sizes, int n_in,
                              void* d_out, int out_size, void* d_ws, size_t ws_size,
                              hipStream_t stream) {
    const float* x   = (const float*)d_in[0];
    const float* Wq  = (const float*)d_in[1];
    const float* bq  = (const float*)d_in[2];
    const float* Wk  = (const float*)d_in[3];
    const float* bk  = (const float*)d_in[4];
    const float* wcq = (const float*)d_in[5];
    const float* wck = (const float*)d_in[6];
    const float* Wv  = (const float*)d_in[7];
    const float* bv  = (const float*)d_in[8];
    const float* Wg  = (const float*)d_in[9];
    const float* bg  = (const float*)d_in[10];
    float* ws  = (float*)d_ws;
    float* out = (float*)d_out;

    // zero barrier counters + global histogram
    hipMemsetAsync(d_ws, 0, (16 + 4 * 4096) * sizeof(int), stream);
    k_fused<<<256, 256, 0, stream>>>(x, Wq, bq, Wk, bk, wcq, wck, Wv, bv, Wg, bg, ws, out);
}

// Round 7
// 137.672 us; speedup vs baseline: 3.0650x; 1.1418x over previous
//
#include <hip/hip_runtime.h>
#include <math.h>

#define NB 4096

// ---- workspace layout (float offsets) ----
#define BARo   0               // 16 ints: grid barrier counters (zeroed by memset)
#define GHo    16              // 4*4096 ints: global histogram (zeroed by memset)
#define Ao     16400           // B*4096
#define Do     32784           // B*4096 (block-local)
#define VGo    49168           // B*4096*64
#define ASo    1097744         // sorted a
#define PERMo  1114128         // int
#define BSTo   1130512         // int, bucket starts
#define Po     1146896         // chunk partials [b][64ch][192gc]
#define PSEAo  1196048         // chunk scalar sum(e^a) [b][64]
#define PSAo   1196304         // chunk scalar sum(a)   [b][64]
#define CPo    1196560         // chunk-prefix tables [b][65q][193] (q*193+g*64+c)
#define CPSEAo 1246740         // [b][65]
#define CPSAo  1247000         // [b][65]
// end = 1247260 floats (~5 MB)

// sc (agent-scope, cache-bypassing) helpers: producers of cross-block data.
// Consumers read CACHED (first touch after barrier => L2 miss => fresh MALL data).
__device__ __forceinline__ float gld(const float* p) {
    return __hip_atomic_load(p, __ATOMIC_RELAXED, __HIP_MEMORY_SCOPE_AGENT);
}
__device__ __forceinline__ void gst(float* p, float v) {
    __hip_atomic_store(p, v, __ATOMIC_RELAXED, __HIP_MEMORY_SCOPE_AGENT);
}
__device__ __forceinline__ void gsti(int* p, int v) {
    __hip_atomic_store(p, v, __ATOMIC_RELAXED, __HIP_MEMORY_SCOPE_AGENT);
}

__device__ __forceinline__ int bucket_of(float v) {
    int k = (int)((v + 16.0f) * 128.0f);
    k = k < 0 ? 0 : k;
    k = k > (NB - 1) ? (NB - 1) : k;
    return k;
}

// Fence-free rendezvous (validated R5/R6). __syncthreads drains vmcnt in every
// wave before lane0 arrives; __threadfence_block = cheap compiler+waitcnt fence
// (workgroup scope: NO cache maintenance) to pin plain loads/stores to phases.
__device__ __forceinline__ void gbar(int* bar, int n) {
    __threadfence_block();
    __syncthreads();
    if (threadIdx.x == 0) {
        __hip_atomic_fetch_add(bar, 1, __ATOMIC_RELAXED, __HIP_MEMORY_SCOPE_AGENT);
        while (__hip_atomic_load(bar, __ATOMIC_RELAXED, __HIP_MEMORY_SCOPE_AGENT) < n)
            __builtin_amdgcn_s_sleep(2);
    }
    __syncthreads();
    __threadfence_block();
}

__global__ __launch_bounds__(256, 1) void k_fused(
        const float* __restrict__ x,
        const float* __restrict__ Wq, const float* __restrict__ bq,
        const float* __restrict__ Wk, const float* __restrict__ bk,
        const float* __restrict__ wcq, const float* __restrict__ wck,
        const float* __restrict__ Wv, const float* __restrict__ bv,
        const float* __restrict__ Wg, const float* __restrict__ bg,
        float* __restrict__ ws, float* __restrict__ out) {
    __shared__ float smem[13056];       // 52.2 KB
    int tid = threadIdx.x;
    int bid = blockIdx.x;
    int b = bid >> 6, t6 = bid & 63;
    int* bar = (int*)ws + BARo;
    int* gh  = (int*)ws + GHo;

    // ===== Phase A: weight prep (redundant per block) + projections + hist =====
    {
        float* xt  = smem;              // [64][68]
        float* wt  = smem + 4352;       // [64][68]: wt[c][o] = Wvg[o][c]
        float* wqe = smem + 8704, *wke = smem + 8768, *bvg = smem + 8832, *misc = smem + 8896;
        if (tid < 64) {
            float s1 = 0.f, s2 = 0.f, s3 = 0.f;
            for (int o = 0; o < 16; o++) { s1 += wcq[o] * Wq[o * 64 + tid]; s2 += wck[o] * Wk[o * 64 + tid]; }
            for (int m = 0; m < 64; m++) s3 += Wg[tid * 64 + m] * bv[m];
            wqe[tid] = s1; wke[tid] = s2; bvg[tid] = s3;
        } else if (tid == 64) {
            float s = 0.f; for (int o = 0; o < 16; o++) s += wcq[o] * bq[o]; misc[0] = s;
        } else if (tid == 65) {
            float s = 0.f; for (int o = 0; o < 16; o++) s += wck[o] * bk[o]; misc[1] = s;
        }
        {
            int o = tid & 63, c0 = (tid >> 6) * 16;
            float acc[16];
#pragma unroll
            for (int k = 0; k < 16; k++) acc[k] = 0.f;
            for (int m = 0; m < 64; m++) {
                float wg = Wg[o * 64 + m];
                const float4* wv4 = (const float4*)(Wv + m * 64 + c0);
                float4 a0 = wv4[0], a1 = wv4[1], a2 = wv4[2], a3 = wv4[3];
                acc[0] += wg * a0.x; acc[1] += wg * a0.y; acc[2] += wg * a0.z; acc[3] += wg * a0.w;
                acc[4] += wg * a1.x; acc[5] += wg * a1.y; acc[6] += wg * a1.z; acc[7] += wg * a1.w;
                acc[8] += wg * a2.x; acc[9] += wg * a2.y; acc[10] += wg * a2.z; acc[11] += wg * a2.w;
                acc[12] += wg * a3.x; acc[13] += wg * a3.y; acc[14] += wg * a3.z; acc[15] += wg * a3.w;
            }
#pragma unroll
            for (int k = 0; k < 16; k++) wt[(c0 + k) * 68 + o] = acc[k];
        }
        const float* xb = x + (size_t)b * 64 * 4096;
        for (int idx = tid; idx < 4096; idx += 256) {
            int c = idx >> 6, nl = idx & 63;
            xt[c * 68 + nl] = xb[(size_t)c * 4096 + t6 * 64 + nl];
        }
        __syncthreads();
        if (tid < 64) {
            float s1 = misc[0], s2 = misc[1];
            for (int c = 0; c < 64; c++) {
                float xv = xt[c * 68 + tid];
                s1 += wqe[c] * xv; s2 += wke[c] * xv;
            }
            gst(&ws[Ao + b * 4096 + t6 * 64 + tid], s1);   // cross-block (B)
            ws[Do + b * 4096 + t6 * 64 + tid] = s2;        // block-local (F)
            atomicAdd(&gh[b * 4096 + bucket_of(s1)], 1);   // device-scope, lands at MALL
        }
        {
            int o = tid & 63, nl0 = (tid >> 6) * 16;
            float acc[16];
            float bo = bvg[o];
#pragma unroll
            for (int k = 0; k < 16; k++) acc[k] = bo;
            for (int c = 0; c < 64; c++) {
                float wv = wt[c * 68 + o];
                const float* xr = &xt[c * 68 + nl0];
#pragma unroll
                for (int k = 0; k < 16; k++) acc[k] += wv * xr[k];
            }
#pragma unroll
            for (int k = 0; k < 16; k++)
                gst(&ws[VGo + ((size_t)(b * 4096) + t6 * 64 + nl0 + k) * 64 + o], acc[k]);
        }
    }
    gbar(&bar[0], 256);

    // ===== Phase B: scan histogram + scatter (4 blocks, one per batch) =====
    if (bid < 4) {
        unsigned int* hist = (unsigned int*)smem;
        unsigned int* cnt  = hist + 4096;
        unsigned int* scanbuf = cnt + 4096;
        int bb = bid;
        const float* Ab = ws + Ao + bb * 4096;     // cached first-touch
        int* perm = (int*)ws + PERMo;
        int* bst  = (int*)ws + BSTo;
#pragma unroll 4
        for (int i = tid; i < NB; i += 256) {
            hist[i] = (unsigned int)gh[bb * 4096 + i];   // cached first-touch
            cnt[i] = 0u;
        }
        __syncthreads();
        unsigned int s = 0u; int base = tid * 16;
        for (int k = 0; k < 16; k++) s += hist[base + k];
        scanbuf[tid] = s;
        __syncthreads();
        for (int off = 1; off < 256; off <<= 1) {
            unsigned int v = scanbuf[tid];
            unsigned int u = (tid >= off) ? scanbuf[tid - off] : 0u;
            __syncthreads();
            scanbuf[tid] = v + u;
            __syncthreads();
        }
        unsigned int run = (tid > 0) ? scanbuf[tid - 1] : 0u;
        for (int k = 0; k < 16; k++) {
            unsigned int h = hist[base + k];
            hist[base + k] = run;
            gsti(&bst[bb * NB + base + k], (int)run);
            run += h;
        }
        __syncthreads();
#pragma unroll 4
        for (int i = tid; i < 4096; i += 256) {
            float av = Ab[i];
            int kb = bucket_of(av);
            unsigned int r = hist[kb] + atomicAdd(&cnt[kb], 1u);
            gst(&ws[ASo + bb * 4096 + r], av);
            gsti(&perm[bb * 4096 + r], (int)i);
        }
    }
    gbar(&bar[1], 256);

    // ===== Phase C: chunk partials (cached reads, sc writes) =====
    {
        int c = tid & 63, w = tid >> 6;
        int r0 = t6 * 64 + w * 16;
        const int* perm = (const int*)ws + PERMo;
        int pk[16]; float avs[16], wvs[16];
#pragma unroll
        for (int k = 0; k < 16; k++) pk[k] = perm[b * 4096 + r0 + k];          // broadcast
#pragma unroll
        for (int k = 0; k < 16; k++) avs[k] = ws[ASo + b * 4096 + r0 + k];     // broadcast
#pragma unroll
        for (int k = 0; k < 16; k++) wvs[k] = ws[VGo + ((size_t)(b * 4096) + pk[k]) * 64 + c];
        float s1 = 0.f, s2 = 0.f, s3 = 0.f, sea_w = 0.f, sa_w = 0.f;
#pragma unroll
        for (int k = 0; k < 16; k++) {
            float ea = expf(avs[k]);
            s1 += wvs[k]; s2 += wvs[k] * ea; s3 += wvs[k] * avs[k];
            sea_w += ea; sa_w += avs[k];
        }
        float* partL = smem;            // [4][3][64]
        float* wsc   = smem + 768;      // [8]
        partL[(w * 3 + 0) * 64 + c] = s1;
        partL[(w * 3 + 1) * 64 + c] = s2;
        partL[(w * 3 + 2) * 64 + c] = s3;
        if (c == 0) { wsc[w] = sea_w; wsc[4 + w] = sa_w; }
        __syncthreads();
        if (tid < 192) {
            int g = tid >> 6, cc = tid & 63;
            float s = partL[(0 * 3 + g) * 64 + cc] + partL[(1 * 3 + g) * 64 + cc]
                    + partL[(2 * 3 + g) * 64 + cc] + partL[(3 * 3 + g) * 64 + cc];
            gst(&ws[Po + (b * 64 + t6) * 192 + tid], s);
        } else if (tid == 192) {
            gst(&ws[PSEAo + b * 64 + t6], wsc[0] + wsc[1] + wsc[2] + wsc[3]);
            gst(&ws[PSAo  + b * 64 + t6], wsc[4] + wsc[5] + wsc[6] + wsc[7]);
        }
    }
    gbar(&bar[2], 256);

    // ===== Phase D: chunk-prefix tables (4 blocks) =====
    if (bid < 4) {
        int bb = bid;
        if (tid < 192) {
            float v[64];
#pragma unroll
            for (int ch = 0; ch < 64; ch++) v[ch] = ws[Po + bb * 12288 + ch * 192 + tid];
            float r = 0.f;
            for (int q = 0; q < 64; q++) {
                gst(&ws[CPo + bb * 12545 + q * 193 + tid], r);
                r += v[q];
            }
            gst(&ws[CPo + bb * 12545 + 64 * 193 + tid], r);
        } else if (tid == 192) {
            float v[64];
#pragma unroll
            for (int ch = 0; ch < 64; ch++) v[ch] = ws[PSEAo + bb * 64 + ch];
            float r = 0.f;
            for (int q = 0; q < 64; q++) { gst(&ws[CPSEAo + bb * 65 + q], r); r += v[q]; }
            gst(&ws[CPSEAo + bb * 65 + 64], r);
        } else if (tid == 193) {
            float v[64];
#pragma unroll
            for (int ch = 0; ch < 64; ch++) v[ch] = ws[PSAo + bb * 64 + ch];
            float r = 0.f;
            for (int q = 0; q < 64; q++) { gst(&ws[CPSAo + bb * 65 + q], r); r += v[q]; }
            gst(&ws[CPSAo + bb * 65 + 64], r);
        }
    }
    gbar(&bar[3], 256);

    // ===== Phase F: cached bulk-load CP -> LDS; snapped-split output =====
    {
        float* cpsea  = smem + 12545;   // [65]
        float* cpsa   = smem + 12610;   // [65]
        float* djs    = smem + 12675;   // [64]
        float* edjs   = smem + 12739;   // [64]
        float* invden = smem + 12803;   // [64]
        int*   qarr   = (int*)(smem + 12867); // [64]
        float* bgs    = smem + 12931;   // [64]
        // bulk cached load of this batch's chunk-prefix table (L2-amortized)
        for (int i = tid; i < 12545; i += 256) smem[i] = ws[CPo + b * 12545 + i];
        if (tid < 65)                     cpsea[tid] = ws[CPSEAo + b * 65 + tid];
        else if (tid >= 128 && tid < 193) cpsa[tid - 128] = ws[CPSAo + b * 65 + tid - 128];
        else if (tid >= 64 && tid < 128)  bgs[tid - 64] = bg[tid - 64];
        __syncthreads();
        const int* bst = (const int*)ws + BSTo;
        int j0 = t6 * 64;
        if (tid < 64) {
            int j = j0 + tid;
            float dj = ws[Do + b * 4096 + j];
            float edj = expf(dj);
            int kb = bucket_of(-dj);
            int t = bst[b * NB + kb];          // cached first-touch
            int q = (t + 32) >> 6;             // snap to chunk boundary
            float den = 1.5f * ((cpsa[64] - cpsa[q]) + dj * (float)(4096 - 64 * q)
                                - (float)(64 * q) + edj * cpsea[q]);
            qarr[tid] = q; djs[tid] = dj; edjs[tid] = edj; invden[tid] = 1.0f / den;
        }
        __syncthreads();
        {
            int jl = tid & 63, cq = tid >> 6;
            float dj = djs[jl], edj = edjs[jl], inv = invden[jl];
            int qb = qarr[jl] * 193;
            for (int cc = cq; cc < 64; cc += 4) {
                float c1 = smem[qb + cc], c2 = smem[qb + 64 + cc], c3 = smem[qb + 128 + cc];
                float t1 = smem[12352 + cc], t3 = smem[12352 + 128 + cc];
                float num = (t3 - c3) + dj * t1 - (1.0f + dj) * c1 + edj * c2;
                out[((size_t)(b * 64 + cc)) * 4096 + j0 + jl] = num * inv + bgs[cc];
            }
        }
    }
}

extern "C" void kernel_launch(void* const* d_in, const int* in_sizes, int n_in,
                              void* d_out, int out_size, void* d_ws, size_t ws_size,
                              hipStream_t stream) {
    const float* x   = (const float*)d_in[0];
    const float* Wq  = (const float*)d_in[1];
    const float* bq  = (const float*)d_in[2];
    const float* Wk  = (const float*)d_in[3];
    const float* bk  = (const float*)d_in[4];
    const float* wcq = (const float*)d_in[5];
    const float* wck = (const float*)d_in[6];
    const float* Wv  = (const float*)d_in[7];
    const float* bv  = (const float*)d_in[8];
    const float* Wg  = (const float*)d_in[9];
    const float* bg  = (const float*)d_in[10];
    float* ws  = (float*)d_ws;
    float* out = (float*)d_out;

    // zero barrier counters + global histogram
    hipMemsetAsync(d_ws, 0, (16 + 4 * 4096) * sizeof(int), stream);
    k_fused<<<256, 256, 0, stream>>>(x, Wq, bq, Wk, bk, wcq, wck, Wv, bv, Wg, bg, ws, out);
}

// Round 8
// 124.476 us; speedup vs baseline: 3.3900x; 1.1060x over previous
//
#include <hip/hip_runtime.h>
#include <math.h>

#define NB 4096

// ---- workspace layout ----
// ints:
#define BARo   0               // 16: barrier counters
#define RELo   16              // 8*32: spread release lines (128B apart)
#define GHo    272             // 4*4096: global histogram
#define GCNTo  16656           // 4*4096: intra-bucket scatter counters
// floats (from 33040):
#define Do     49424           // B*4096 (block-local)
#define VGo    65808           // B*4096*64
#define ASo    1114384         // sorted a
#define PERMo  1130768         // int
#define BSTo   1147152         // int, bucket starts (published by t6==0)
#define Po     1163536         // chunk partials [b][64ch][192]
#define PSEAo  1212688         // [b][64]
#define PSAo   1212944         // [b][64]
#define CPo    1213200         // chunk-prefix tables [b][65q][193]
#define CPSEAo 1263380         // [b][65]
#define CPSAo  1263640         // [b][65]
#define MEMSET_BYTES 132160    // 33040 ints

__device__ __forceinline__ float gld(const float* p) {
    return __hip_atomic_load(p, __ATOMIC_RELAXED, __HIP_MEMORY_SCOPE_AGENT);
}
__device__ __forceinline__ void gst(float* p, float v) {
    __hip_atomic_store(p, v, __ATOMIC_RELAXED, __HIP_MEMORY_SCOPE_AGENT);
}
__device__ __forceinline__ void gsti(int* p, int v) {
    __hip_atomic_store(p, v, __ATOMIC_RELAXED, __HIP_MEMORY_SCOPE_AGENT);
}

__device__ __forceinline__ int bucket_of(float v) {
    int k = (int)((v + 16.0f) * 128.0f);
    k = k < 0 ? 0 : k;
    k = k > (NB - 1) ? (NB - 1) : k;
    return k;
}

// Spread-release barrier: one fetch_add per block; LAST arriver broadcasts the
// phase number to 8 release lines 128B apart; pollers watch rel[bid&7] only.
// ~32 pollers/line over 8 MALL channels (vs 256 on one line = R7's stall).
__device__ __forceinline__ void gbar(int* wsi, int idx, int n) {
    __syncthreads();
    if (threadIdx.x == 0) {
        int old = __hip_atomic_fetch_add(wsi + BARo + idx, 1, __ATOMIC_RELAXED,
                                         __HIP_MEMORY_SCOPE_AGENT);
        if (old == n - 1) {
#pragma unroll
            for (int i = 0; i < 8; i++)
                __hip_atomic_store(wsi + RELo + i * 32, idx + 1, __ATOMIC_RELAXED,
                                   __HIP_MEMORY_SCOPE_AGENT);
        } else {
            const int* myrel = wsi + RELo + (blockIdx.x & 7) * 32;
            while (__hip_atomic_load(myrel, __ATOMIC_RELAXED, __HIP_MEMORY_SCOPE_AGENT) <= idx)
                __builtin_amdgcn_s_sleep(8);
        }
    }
    __syncthreads();
}

__global__ __launch_bounds__(256, 1) void k_fused(
        const float* __restrict__ x,
        const float* __restrict__ Wq, const float* __restrict__ bq,
        const float* __restrict__ Wk, const float* __restrict__ bk,
        const float* __restrict__ wcq, const float* __restrict__ wck,
        const float* __restrict__ Wv, const float* __restrict__ bv,
        const float* __restrict__ Wg, const float* __restrict__ bg,
        float* __restrict__ ws, float* __restrict__ out) {
    __shared__ float smem[13056];       // 52.2 KB
    int tid = threadIdx.x;
    int bid = blockIdx.x;
    int b = bid >> 6, t6 = bid & 63;
    int* wsi = (int*)ws;
    int* gh  = wsi + GHo;

    float myA = 0.f;                    // a for pixel t6*64+tid (tid<64), reg-resident

    // ===== Phase A: weight prep (redundant) + projections + histogram =====
    {
        float* xt  = smem;              // [64][68]
        float* wt  = smem + 4352;       // [64][68]: wt[c][o] = Wvg[o][c]
        float* wqe = smem + 8704, *wke = smem + 8768, *bvg = smem + 8832, *misc = smem + 8896;
        if (tid < 64) {
            float s1 = 0.f, s2 = 0.f, s3 = 0.f;
            for (int o = 0; o < 16; o++) { s1 += wcq[o] * Wq[o * 64 + tid]; s2 += wck[o] * Wk[o * 64 + tid]; }
            for (int m = 0; m < 64; m++) s3 += Wg[tid * 64 + m] * bv[m];
            wqe[tid] = s1; wke[tid] = s2; bvg[tid] = s3;
        } else if (tid == 64) {
            float s = 0.f; for (int o = 0; o < 16; o++) s += wcq[o] * bq[o]; misc[0] = s;
        } else if (tid == 65) {
            float s = 0.f; for (int o = 0; o < 16; o++) s += wck[o] * bk[o]; misc[1] = s;
        }
        {
            int o = tid & 63, c0 = (tid >> 6) * 16;
            float acc[16];
#pragma unroll
            for (int k = 0; k < 16; k++) acc[k] = 0.f;
            for (int m = 0; m < 64; m++) {
                float wg = Wg[o * 64 + m];
                const float4* wv4 = (const float4*)(Wv + m * 64 + c0);
                float4 a0 = wv4[0], a1 = wv4[1], a2 = wv4[2], a3 = wv4[3];
                acc[0] += wg * a0.x; acc[1] += wg * a0.y; acc[2] += wg * a0.z; acc[3] += wg * a0.w;
                acc[4] += wg * a1.x; acc[5] += wg * a1.y; acc[6] += wg * a1.z; acc[7] += wg * a1.w;
                acc[8] += wg * a2.x; acc[9] += wg * a2.y; acc[10] += wg * a2.z; acc[11] += wg * a2.w;
                acc[12] += wg * a3.x; acc[13] += wg * a3.y; acc[14] += wg * a3.z; acc[15] += wg * a3.w;
            }
#pragma unroll
            for (int k = 0; k < 16; k++) wt[(c0 + k) * 68 + o] = acc[k];
        }
        const float* xb = x + (size_t)b * 64 * 4096;
        for (int idx = tid; idx < 4096; idx += 256) {
            int c = idx >> 6, nl = idx & 63;
            xt[c * 68 + nl] = xb[(size_t)c * 4096 + t6 * 64 + nl];
        }
        __syncthreads();
        if (tid < 64) {
            float s1 = misc[0], s2 = misc[1];
            for (int c = 0; c < 64; c++) {
                float xv = xt[c * 68 + tid];
                s1 += wqe[c] * xv; s2 += wke[c] * xv;
            }
            myA = s1;
            ws[Do + b * 4096 + t6 * 64 + tid] = s2;        // block-local (F)
            atomicAdd(&gh[b * 4096 + bucket_of(s1)], 1);   // device-scope -> MALL
        }
        {
            int o = tid & 63, nl0 = (tid >> 6) * 16;
            float acc[16];
            float bo = bvg[o];
#pragma unroll
            for (int k = 0; k < 16; k++) acc[k] = bo;
            for (int c = 0; c < 64; c++) {
                float wv = wt[c * 68 + o];
                const float* xr = &xt[c * 68 + nl0];
#pragma unroll
                for (int k = 0; k < 16; k++) acc[k] += wv * xr[k];
            }
#pragma unroll
            for (int k = 0; k < 16; k++)
                gst(&ws[VGo + ((size_t)(b * 4096) + t6 * 64 + nl0 + k) * 64 + o], acc[k]);
        }
    }
    gbar(wsi, 0, 256);

    // ===== Phase B: redundant per-block scan + distributed scatter =====
    {
        unsigned int* hist = (unsigned int*)smem;          // [4096]
        unsigned int* scanbuf = hist + 4096;               // [256]
        const int* gh_b = gh + b * 4096;
        int* gcnt = wsi + GCNTo + b * 4096;
#pragma unroll 4
        for (int i = tid; i < NB; i += 256) hist[i] = (unsigned int)gh_b[i];  // cached first-touch
        __syncthreads();
        unsigned int s = 0u; int base = tid * 16;
        for (int k = 0; k < 16; k++) s += hist[base + k];
        scanbuf[tid] = s;
        __syncthreads();
        for (int off = 1; off < 256; off <<= 1) {
            unsigned int v = scanbuf[tid];
            unsigned int u = (tid >= off) ? scanbuf[tid - off] : 0u;
            __syncthreads();
            scanbuf[tid] = v + u;
            __syncthreads();
        }
        unsigned int run = (tid > 0) ? scanbuf[tid - 1] : 0u;
        for (int k = 0; k < 16; k++) {
            unsigned int h = hist[base + k];
            hist[base + k] = run;       // hist now holds bucket starts
            run += h;
        }
        __syncthreads();
        if (t6 == 0) {                   // publish bst once per batch (for F)
            int* bst = wsi + BSTo;
#pragma unroll 4
            for (int i = tid; i < NB; i += 256) gsti(&bst[b * 4096 + i], (int)hist[i]);
        }
        if (tid < 64) {                  // scatter my own pixel (a in register)
            int i = t6 * 64 + tid;
            int kb = bucket_of(myA);
            int r = (int)hist[kb] + atomicAdd(&gcnt[kb], 1);
            gst(&ws[ASo + b * 4096 + r], myA);
            gsti((int*)ws + PERMo + b * 4096 + r, i);
        }
    }
    gbar(wsi, 1, 256);

    // ===== Phase C: chunk partials (cached reads, sc writes) =====
    {
        int c = tid & 63, w = tid >> 6;
        int r0 = t6 * 64 + w * 16;
        const int* perm = (const int*)ws + PERMo;
        int pk[16]; float avs[16], wvs[16];
#pragma unroll
        for (int k = 0; k < 16; k++) pk[k] = perm[b * 4096 + r0 + k];
#pragma unroll
        for (int k = 0; k < 16; k++) avs[k] = ws[ASo + b * 4096 + r0 + k];
#pragma unroll
        for (int k = 0; k < 16; k++) wvs[k] = ws[VGo + ((size_t)(b * 4096) + pk[k]) * 64 + c];
        float s1 = 0.f, s2 = 0.f, s3 = 0.f, sea_w = 0.f, sa_w = 0.f;
#pragma unroll
        for (int k = 0; k < 16; k++) {
            float ea = expf(avs[k]);
            s1 += wvs[k]; s2 += wvs[k] * ea; s3 += wvs[k] * avs[k];
            sea_w += ea; sa_w += avs[k];
        }
        float* partL = smem;            // [4][3][64]
        float* wsc   = smem + 768;      // [8]
        partL[(w * 3 + 0) * 64 + c] = s1;
        partL[(w * 3 + 1) * 64 + c] = s2;
        partL[(w * 3 + 2) * 64 + c] = s3;
        if (c == 0) { wsc[w] = sea_w; wsc[4 + w] = sa_w; }
        __syncthreads();
        if (tid < 192) {
            int g = tid >> 6, cc = tid & 63;
            float s = partL[(0 * 3 + g) * 64 + cc] + partL[(1 * 3 + g) * 64 + cc]
                    + partL[(2 * 3 + g) * 64 + cc] + partL[(3 * 3 + g) * 64 + cc];
            gst(&ws[Po + (b * 64 + t6) * 192 + tid], s);
        } else if (tid == 192) {
            gst(&ws[PSEAo + b * 64 + t6], wsc[0] + wsc[1] + wsc[2] + wsc[3]);
            gst(&ws[PSAo  + b * 64 + t6], wsc[4] + wsc[5] + wsc[6] + wsc[7]);
        }
    }
    gbar(wsi, 2, 256);

    // ===== Phase D: distributed chunk-prefix: block (b,q=t6) sums ch<q =====
    {
        if (tid < 192) {
            float s = 0.f;
#pragma unroll 8
            for (int ch = 0; ch < t6; ch++) s += ws[Po + b * 12288 + ch * 192 + tid];  // cached
            gst(&ws[CPo + b * 12545 + t6 * 193 + tid], s);
            if (t6 == 63) {
                s += ws[Po + b * 12288 + 63 * 192 + tid];
                gst(&ws[CPo + b * 12545 + 64 * 193 + tid], s);
            }
        } else if (tid == 192) {
            float s = 0.f;
            for (int ch = 0; ch < t6; ch++) s += ws[PSEAo + b * 64 + ch];
            gst(&ws[CPSEAo + b * 65 + t6], s);
            if (t6 == 63) { s += ws[PSEAo + b * 64 + 63]; gst(&ws[CPSEAo + b * 65 + 64], s); }
        } else if (tid == 193) {
            float s = 0.f;
            for (int ch = 0; ch < t6; ch++) s += ws[PSAo + b * 64 + ch];
            gst(&ws[CPSAo + b * 65 + t6], s);
            if (t6 == 63) { s += ws[PSAo + b * 64 + 63]; gst(&ws[CPSAo + b * 65 + 64], s); }
        }
    }
    gbar(wsi, 3, 256);

    // ===== Phase F: cached bulk-load CP -> LDS; snapped-split output =====
    {
        float* cpsea  = smem + 12545;   // [65]
        float* cpsa   = smem + 12610;   // [65]
        float* djs    = smem + 12675;   // [64]
        float* edjs   = smem + 12739;   // [64]
        float* invden = smem + 12803;   // [64]
        int*   qarr   = (int*)(smem + 12867); // [64]
        float* bgs    = smem + 12931;   // [64]
        for (int i = tid; i < 12545; i += 256) smem[i] = ws[CPo + b * 12545 + i];   // cached
        if (tid < 65)                     cpsea[tid] = ws[CPSEAo + b * 65 + tid];
        else if (tid >= 128 && tid < 193) cpsa[tid - 128] = ws[CPSAo + b * 65 + tid - 128];
        else if (tid >= 64 && tid < 128)  bgs[tid - 64] = bg[tid - 64];
        __syncthreads();
        const int* bst = (const int*)ws + BSTo;
        int j0 = t6 * 64;
        if (tid < 64) {
            int j = j0 + tid;
            float dj = ws[Do + b * 4096 + j];
            float edj = expf(dj);
            int kb = bucket_of(-dj);
            int t = bst[b * NB + kb];          // cached first-touch
            int q = (t + 32) >> 6;             // snap to chunk boundary
            float den = 1.5f * ((cpsa[64] - cpsa[q]) + dj * (float)(4096 - 64 * q)
                                - (float)(64 * q) + edj * cpsea[q]);
            qarr[tid] = q; djs[tid] = dj; edjs[tid] = edj; invden[tid] = 1.0f / den;
        }
        __syncthreads();
        {
            int jl = tid & 63, cq = tid >> 6;
            float dj = djs[jl], edj = edjs[jl], inv = invden[jl];
            int qb = qarr[jl] * 193;
            for (int cc = cq; cc < 64; cc += 4) {
                float c1 = smem[qb + cc], c2 = smem[qb + 64 + cc], c3 = smem[qb + 128 + cc];
                float t1 = smem[12352 + cc], t3 = smem[12352 + 128 + cc];
                float num = (t3 - c3) + dj * t1 - (1.0f + dj) * c1 + edj * c2;
                out[((size_t)(b * 64 + cc)) * 4096 + j0 + jl] = num * inv + bgs[cc];
            }
        }
    }
}

extern "C" void kernel_launch(void* const* d_in, const int* in_sizes, int n_in,
                              void* d_out, int out_size, void* d_ws, size_t ws_size,
                              hipStream_t stream) {
    const float* x   = (const float*)d_in[0];
    const float* Wq  = (const float*)d_in[1];
    const float* bq  = (const float*)d_in[2];
    const float* Wk  = (const float*)d_in[3];
    const float* bk  = (const float*)d_in[4];
    const float* wcq = (const float*)d_in[5];
    const float* wck = (const float*)d_in[6];
    const float* Wv  = (const float*)d_in[7];
    const float* bv  = (const float*)d_in[8];
    const float* Wg  = (const float*)d_in[9];
    const float* bg  = (const float*)d_in[10];
    float* ws  = (float*)d_ws;
    float* out = (float*)d_out;

    // zero barrier counters + release lines + histogram + scatter counters
    hipMemsetAsync(d_ws, 0, MEMSET_BYTES, stream);
    k_fused<<<256, 256, 0, stream>>>(x, Wq, bq, Wk, bk, wcq, wck, Wv, bv, Wg, bg, ws, out);
}

// Round 9
// 107.185 us; speedup vs baseline: 3.9368x; 1.1613x over previous
//
#include <hip/hip_runtime.h>
#include <math.h>

#define NB 4096

// ---- workspace layout ----
// ints:
#define LEAFo  0               // 3 barriers * 8 leaves * 32 ints (128B spacing)
#define MASTo  768             // 3 * 32
#define RELo   864             // 8 * 32 spread release lines
#define GHo    1120            // 4*4096 histogram
#define GCNTo  17504           // 4*4096 scatter counters
#define MEMSET_BYTES 135552    // 33888 ints
// floats:
#define Do     33888           // B*4096 (block-local)
#define VGo    50272           // B*4096*64
#define ASo    1098848         // sorted a
#define PERMo  1115232         // int
#define BSTo   1131616         // int, bucket starts
#define Po     1148000         // chunk partials [b][64ch][192]
#define PSEAo  1197152         // [b][64]
#define PSAo   1197408         // [b][64]

__device__ __forceinline__ void gst(float* p, float v) {
    __hip_atomic_store(p, v, __ATOMIC_RELAXED, __HIP_MEMORY_SCOPE_AGENT);
}
__device__ __forceinline__ void gsti(int* p, int v) {
    __hip_atomic_store(p, v, __ATOMIC_RELAXED, __HIP_MEMORY_SCOPE_AGENT);
}

__device__ __forceinline__ int bucket_of(float v) {
    int k = (int)((v + 16.0f) * 128.0f);
    k = k < 0 ? 0 : k;
    k = k > (NB - 1) ? (NB - 1) : k;
    return k;
}

// Tree-arrival barrier: 32 contenders per leaf line, 8 per master, release on
// 8 spread lines. All same-line MALL queues stay short.
__device__ __forceinline__ void gbar(int* wsi, int idx) {
    __syncthreads();
    if (threadIdx.x == 0) {
        int leaf = blockIdx.x & 7;
        bool bcast = false;
        int old = __hip_atomic_fetch_add(wsi + LEAFo + (idx * 8 + leaf) * 32, 1,
                                         __ATOMIC_RELAXED, __HIP_MEMORY_SCOPE_AGENT);
        if (old == 31) {
            int m = __hip_atomic_fetch_add(wsi + MASTo + idx * 32, 1,
                                           __ATOMIC_RELAXED, __HIP_MEMORY_SCOPE_AGENT);
            if (m == 7) {
#pragma unroll
                for (int i = 0; i < 8; i++)
                    __hip_atomic_store(wsi + RELo + i * 32, idx + 1,
                                       __ATOMIC_RELAXED, __HIP_MEMORY_SCOPE_AGENT);
                bcast = true;
            }
        }
        if (!bcast) {
            const int* myrel = wsi + RELo + leaf * 32;
            while (__hip_atomic_load(myrel, __ATOMIC_RELAXED, __HIP_MEMORY_SCOPE_AGENT) <= idx)
                __builtin_amdgcn_s_sleep(8);
        }
    }
    __syncthreads();
}

__global__ __launch_bounds__(256, 1) void k_fused(
        const float* __restrict__ x,
        const float* __restrict__ Wq, const float* __restrict__ bq,
        const float* __restrict__ Wk, const float* __restrict__ bk,
        const float* __restrict__ wcq, const float* __restrict__ wck,
        const float* __restrict__ Wv, const float* __restrict__ bv,
        const float* __restrict__ Wg, const float* __restrict__ bg,
        float* __restrict__ ws, float* __restrict__ out) {
    __shared__ float smem[13056];       // 52.2 KB
    int tid = threadIdx.x;
    int bid = blockIdx.x;
    int b = bid >> 6, t6 = bid & 63;
    int* wsi = (int*)ws;
    int* gh  = wsi + GHo;

    float myA = 0.f;                    // a for pixel t6*64+tid (tid<64)

    // ===== Phase A: weight prep (redundant) + projections + histogram =====
    {
        float* xt  = smem;              // [64][72] (16B-aligned rows)
        float* wt  = smem + 4608;       // [64][72]: wt[c][o] = Wvg[o][c]
        float* wqe = smem + 9216, *wke = smem + 9280, *bvg = smem + 9344, *misc = smem + 9408;
        if (tid < 64) {
            float s1 = 0.f, s2 = 0.f, s3 = 0.f;
            for (int o = 0; o < 16; o++) { s1 += wcq[o] * Wq[o * 64 + tid]; s2 += wck[o] * Wk[o * 64 + tid]; }
            for (int m = 0; m < 64; m++) s3 += Wg[tid * 64 + m] * bv[m];
            wqe[tid] = s1; wke[tid] = s2; bvg[tid] = s3;
        } else if (tid == 64) {
            float s = 0.f; for (int o = 0; o < 16; o++) s += wcq[o] * bq[o]; misc[0] = s;
        } else if (tid == 65) {
            float s = 0.f; for (int o = 0; o < 16; o++) s += wck[o] * bk[o]; misc[1] = s;
        }
        {
            int o = tid & 63, c0 = (tid >> 6) * 16;
            float acc[16];
#pragma unroll
            for (int k = 0; k < 16; k++) acc[k] = 0.f;
            for (int m = 0; m < 64; m++) {
                float wg = Wg[o * 64 + m];
                const float4* wv4 = (const float4*)(Wv + m * 64 + c0);
                float4 a0 = wv4[0], a1 = wv4[1], a2 = wv4[2], a3 = wv4[3];
                acc[0] += wg * a0.x; acc[1] += wg * a0.y; acc[2] += wg * a0.z; acc[3] += wg * a0.w;
                acc[4] += wg * a1.x; acc[5] += wg * a1.y; acc[6] += wg * a1.z; acc[7] += wg * a1.w;
                acc[8] += wg * a2.x; acc[9] += wg * a2.y; acc[10] += wg * a2.z; acc[11] += wg * a2.w;
                acc[12] += wg * a3.x; acc[13] += wg * a3.y; acc[14] += wg * a3.z; acc[15] += wg * a3.w;
            }
#pragma unroll
            for (int k = 0; k < 16; k++) wt[(c0 + k) * 72 + o] = acc[k];
        }
        const float4* xb4 = (const float4*)(x + (size_t)b * 64 * 4096);
#pragma unroll
        for (int idx = tid; idx < 1024; idx += 256) {
            int c = idx >> 4, nl4 = idx & 15;
            *(float4*)&xt[c * 72 + nl4 * 4] = xb4[c * 1024 + t6 * 16 + nl4];
        }
        __syncthreads();
        if (tid < 64) {
            float s1 = misc[0], s2 = misc[1];
            for (int c = 0; c < 64; c++) {
                float xv = xt[c * 72 + tid];
                s1 += wqe[c] * xv; s2 += wke[c] * xv;
            }
            myA = s1;
            ws[Do + b * 4096 + t6 * 64 + tid] = s2;        // block-local (F)
            atomicAdd(&gh[b * 4096 + bucket_of(s1)], 1);   // device-scope -> MALL
        }
        {
            int o = tid & 63, nl0 = (tid >> 6) * 16;
            float acc[16];
            float bo = bvg[o];
#pragma unroll
            for (int k = 0; k < 16; k++) acc[k] = bo;
            for (int c = 0; c < 64; c++) {
                float wv = wt[c * 72 + o];
                const float* xr = &xt[c * 72 + nl0];
#pragma unroll
                for (int k = 0; k < 16; k++) acc[k] += wv * xr[k];
            }
#pragma unroll
            for (int k = 0; k < 16; k++)
                gst(&ws[VGo + ((size_t)(b * 4096) + t6 * 64 + nl0 + k) * 64 + o], acc[k]);
        }
    }
    gbar(wsi, 0);

    // ===== Phase B: per-block shfl scan + distributed scatter =====
    {
        unsigned int* hist = (unsigned int*)smem;          // [4096]
        unsigned int* wtot = hist + 4096;                  // [4]
        const int* gh_b = gh + b * 4096;
        int* gcnt = wsi + GCNTo + b * 4096;
#pragma unroll 4
        for (int i = tid; i < NB; i += 256) hist[i] = (unsigned int)gh_b[i];  // cached first-touch
        __syncthreads();
        int lane = tid & 63, w = tid >> 6;
        unsigned int s = 0u; int base = tid * 16;
#pragma unroll
        for (int k = 0; k < 16; k++) s += hist[base + k];
        unsigned int inc = s;
        for (int off = 1; off < 64; off <<= 1) {
            unsigned int u = __shfl_up(inc, off);
            if (lane >= off) inc += u;
        }
        if (lane == 63) wtot[w] = inc;
        __syncthreads();
        unsigned int run = inc - s;
        for (int w2 = 0; w2 < w; w2++) run += wtot[w2];
        for (int k = 0; k < 16; k++) {
            unsigned int h = hist[base + k];
            hist[base + k] = run;       // hist now holds bucket starts
            run += h;
        }
        __syncthreads();
        if (t6 == 0) {                   // publish bst once per batch (for F)
            int* bst = wsi + BSTo;
#pragma unroll 4
            for (int i = tid; i < NB; i += 256) gsti(&bst[b * 4096 + i], (int)hist[i]);
        }
        if (tid < 64) {                  // scatter own pixel (a in register)
            int i = t6 * 64 + tid;
            int kb = bucket_of(myA);
            int r = (int)hist[kb] + atomicAdd(&gcnt[kb], 1);
            gst(&ws[ASo + b * 4096 + r], myA);
            gsti((int*)ws + PERMo + b * 4096 + r, i);
        }
    }
    gbar(wsi, 1);

    // ===== Phase C: chunk partials (cached reads, sc writes) =====
    {
        int c = tid & 63, w = tid >> 6;
        int r0 = t6 * 64 + w * 16;
        const int* perm = (const int*)ws + PERMo;
        int pk[16]; float avs[16], wvs[16];
#pragma unroll
        for (int k = 0; k < 16; k++) pk[k] = perm[b * 4096 + r0 + k];
#pragma unroll
        for (int k = 0; k < 16; k++) avs[k] = ws[ASo + b * 4096 + r0 + k];
#pragma unroll
        for (int k = 0; k < 16; k++) wvs[k] = ws[VGo + ((size_t)(b * 4096) + pk[k]) * 64 + c];
        float s1 = 0.f, s2 = 0.f, s3 = 0.f, sea_w = 0.f, sa_w = 0.f;
#pragma unroll
        for (int k = 0; k < 16; k++) {
            float ea = expf(avs[k]);
            s1 += wvs[k]; s2 += wvs[k] * ea; s3 += wvs[k] * avs[k];
            sea_w += ea; sa_w += avs[k];
        }
        float* partL = smem;            // [4][3][64]
        float* wsc   = smem + 768;      // [8]
        partL[(w * 3 + 0) * 64 + c] = s1;
        partL[(w * 3 + 1) * 64 + c] = s2;
        partL[(w * 3 + 2) * 64 + c] = s3;
        if (c == 0) { wsc[w] = sea_w; wsc[4 + w] = sa_w; }
        __syncthreads();
        if (tid < 192) {
            int g = tid >> 6, cc = tid & 63;
            float s = partL[(0 * 3 + g) * 64 + cc] + partL[(1 * 3 + g) * 64 + cc]
                    + partL[(2 * 3 + g) * 64 + cc] + partL[(3 * 3 + g) * 64 + cc];
            gst(&ws[Po + (b * 64 + t6) * 192 + tid], s);
        } else if (tid == 192) {
            gst(&ws[PSEAo + b * 64 + t6], wsc[0] + wsc[1] + wsc[2] + wsc[3]);
            gst(&ws[PSAo  + b * 64 + t6], wsc[4] + wsc[5] + wsc[6] + wsc[7]);
        }
    }
    gbar(wsi, 2);

    // ===== Phase F: per-block chunk-prefix (reg prefetch) + output =====
    {
        float* CP     = smem;                  // [65][193]
        float* cpsea  = smem + 12545;          // [65]
        float* cpsa   = smem + 12610;          // [65]
        float* djs    = smem + 12675;          // [64]
        float* edjs   = smem + 12739;          // [64]
        float* invden = smem + 12803;          // [64]
        int*   qarr   = (int*)(smem + 12867);  // [64]
        float* bgs    = smem + 12931;          // [64]
        if (tid < 192) {
            float v[64];
#pragma unroll
            for (int ch = 0; ch < 64; ch++) v[ch] = ws[Po + b * 12288 + ch * 192 + tid]; // cached
            float r = 0.f;
#pragma unroll
            for (int q = 0; q < 64; q++) { CP[q * 193 + tid] = r; r += v[q]; }
            CP[64 * 193 + tid] = r;
        } else if (tid == 192) {
            float v[64];
#pragma unroll
            for (int ch = 0; ch < 64; ch++) v[ch] = ws[PSEAo + b * 64 + ch];
            float r = 0.f;
#pragma unroll
            for (int q = 0; q < 64; q++) { cpsea[q] = r; r += v[q]; }
            cpsea[64] = r;
        } else if (tid == 193) {
            float v[64];
#pragma unroll
            for (int ch = 0; ch < 64; ch++) v[ch] = ws[PSAo + b * 64 + ch];
            float r = 0.f;
#pragma unroll
            for (int q = 0; q < 64; q++) { cpsa[q] = r; r += v[q]; }
            cpsa[64] = r;
        } else if (tid >= 194 && tid < 258) {
            // spare lanes idle
        }
        if (tid >= 194 - 64 && tid < 194) { }
        if (tid < 64) bgs[tid] = bg[tid];
        __syncthreads();
        const int* bst = (const int*)ws + BSTo;
        int j0 = t6 * 64;
        if (tid < 64) {
            int j = j0 + tid;
            float dj = ws[Do + b * 4096 + j];
            float edj = expf(dj);
            int kb = bucket_of(-dj);
            int t = bst[b * NB + kb];          // cached first-touch
            int q = (t + 32) >> 6;             // snap to chunk boundary
            float den = 1.5f * ((cpsa[64] - cpsa[q]) + dj * (float)(4096 - 64 * q)
                                - (float)(64 * q) + edj * cpsea[q]);
            qarr[tid] = q; djs[tid] = dj; edjs[tid] = edj; invden[tid] = 1.0f / den;
        }
        __syncthreads();
        {
            int jl = tid & 63, cq = tid >> 6;
            float dj = djs[jl], edj = edjs[jl], inv = invden[jl];
            int qb = qarr[jl] * 193;
            for (int cc = cq; cc < 64; cc += 4) {
                float c1 = CP[qb + cc], c2 = CP[qb + 64 + cc], c3 = CP[qb + 128 + cc];
                float t1 = CP[64 * 193 + cc], t3 = CP[64 * 193 + 128 + cc];
                float num = (t3 - c3) + dj * t1 - (1.0f + dj) * c1 + edj * c2;
                out[((size_t)(b * 64 + cc)) * 4096 + j0 + jl] = num * inv + bgs[cc];
            }
        }
    }
}

extern "C" void kernel_launch(void* const* d_in, const int* in_sizes, int n_in,
                              void* d_out, int out_size, void* d_ws, size_t ws_size,
                              hipStream_t stream) {
    const float* x   = (const float*)d_in[0];
    const float* Wq  = (const float*)d_in[1];
    const float* bq  = (const float*)d_in[2];
    const float* Wk  = (const float*)d_in[3];
    const float* bk  = (const float*)d_in[4];
    const float* wcq = (const float*)d_in[5];
    const float* wck = (const float*)d_in[6];
    const float* Wv  = (const float*)d_in[7];
    const float* bv  = (const float*)d_in[8];
    const float* Wg  = (const float*)d_in[9];
    const float* bg  = (const float*)d_in[10];
    float* ws  = (float*)d_ws;
    float* out = (float*)d_out;

    hipMemsetAsync(d_ws, 0, MEMSET_BYTES, stream);
    k_fused<<<256, 256, 0, stream>>>(x, Wq, bq, Wk, bk, wcq, wck, Wv, bv, Wg, bg, ws, out);
}